// Round 1
// baseline (551.095 us; speedup 1.0000x reference)
//
#include <hip/hip_runtime.h>
#include <math.h>

#define KTOT 1152   // 128 (silu base) + 1024 (128 features x 8 spline bases)

__device__ __forceinline__ float siluf(float x) {
    return x / (1.0f + __expf(-x));
}

// cubic B-spline bases on the fixed uniform grid (GRID_SIZE=5, order=3)
__device__ __forceinline__ void bspline8(float x, float* out) {
    float g[12];
#pragma unroll
    for (int i = 0; i < 12; ++i) g[i] = (float)(i - 3) * 0.4f - 1.0f;
    float b[11];
#pragma unroll
    for (int i = 0; i < 11; ++i) b[i] = (x >= g[i] && x < g[i + 1]) ? 1.0f : 0.0f;
#pragma unroll
    for (int k = 1; k <= 3; ++k) {
#pragma unroll
        for (int i = 0; i + k < 11; ++i) {
            // grid values are compile-time constants -> reciprocals fold at compile time
            float left  = (x - g[i]) * (1.0f / (g[i + k] - g[i]));
            float right = (g[i + k + 1] - x) * (1.0f / (g[i + k + 1] - g[i + 1]));
            b[i] = left * b[i] + right * b[i + 1];
        }
    }
#pragma unroll
    for (int c = 0; c < 8; ++c) out[c] = b[c];
}

// ---------- wa = W @ a halves: wa[0:128]=W@a[:128], wa[128:256]=W@a[128:] ----------
__global__ void k_wa(const float* __restrict__ W, const float* __restrict__ a,
                     float* __restrict__ wa) {
    int fi = threadIdx.x;  // 128 threads
    float s1 = 0.f, s2 = 0.f;
    for (int o = 0; o < 128; ++o) {
        float w = W[fi * 128 + o];
        s1 = fmaf(w, a[o], s1);
        s2 = fmaf(w, a[128 + o], s2);
    }
    wa[fi] = s1;
    wa[128 + fi] = s2;
}

// ---------- Bt[k][o], k<128: base_weight[o][k]; k>=128: spline_weight[o][k-128] ----------
__global__ void k_prep(const float* __restrict__ bw, const float* __restrict__ sw,
                       float* __restrict__ Bt) {
    int i = blockIdx.x * 256 + threadIdx.x;
    if (i >= KTOT * 128) return;
    int k = i >> 7, o = i & 127;
    Bt[i] = (k < 128) ? bw[o * 128 + k] : sw[o * 1024 + (k - 128)];
}

// ---------- main node kernel: kan[n][o] = silu(h[n])@BWt + bases(h[n])@SWt ----------
// block tile: 32 nodes x 128 outs, 256 threads, 4x4 register tile per thread
__global__ __launch_bounds__(256) void k_nodes(const float* __restrict__ h,
                                               const float* __restrict__ Bt,
                                               float* __restrict__ kan, int N) {
    __shared__ float h_lds[32][129];  // +1 pad: bank-conflict-free column reads
    __shared__ float Al[128 * 32];    // k-major A chunk [128 k][32 nodes]
    const int tid = threadIdx.x;
    const int gn0 = blockIdx.x * 32;

    for (int i = tid; i < 32 * 128; i += 256) {
        int n = i >> 7, k = i & 127;
        int row = gn0 + n;
        if (row >= N) row = N - 1;
        h_lds[n][k] = h[(size_t)row * 128 + k];
    }

    const int o_idx = tid & 31, n_idx = tid >> 5;
    const int n0 = n_idx * 4, o0 = o_idx * 4;
    float4 acc0 = make_float4(0.f, 0.f, 0.f, 0.f);
    float4 acc1 = acc0, acc2 = acc0, acc3 = acc0;
    __syncthreads();

    for (int chunk = 0; chunk < 9; ++chunk) {
        if (chunk == 0) {
            // k=0..127: silu(h) features
            for (int i = tid; i < 4096; i += 256) {
                int n = i & 31, k = i >> 5;
                float x = h_lds[n][k];
                Al[k * 32 + n] = siluf(x);
            }
        } else {
            // k=128+fi*8+c: spline bases, 16 features per chunk
            int fib = (chunk - 1) * 16;
            for (int p = tid; p < 512; p += 256) {
                int n = p & 31, fl = p >> 5;
                float x = h_lds[n][fib + fl];
                float b[8];
                bspline8(x, b);
                int kb = fl * 8;
#pragma unroll
                for (int c = 0; c < 8; ++c) Al[(kb + c) * 32 + n] = b[c];
            }
        }
        __syncthreads();

        const float* __restrict__ Brow = Bt + (size_t)chunk * (128 * 128);
#pragma unroll 4
        for (int k = 0; k < 128; ++k) {
            const float4 wv = *(const float4*)(Brow + k * 128 + o0);
            const float4 av = *(const float4*)(Al + k * 32 + n0);
            acc0.x = fmaf(av.x, wv.x, acc0.x);
            acc0.y = fmaf(av.x, wv.y, acc0.y);
            acc0.z = fmaf(av.x, wv.z, acc0.z);
            acc0.w = fmaf(av.x, wv.w, acc0.w);
            acc1.x = fmaf(av.y, wv.x, acc1.x);
            acc1.y = fmaf(av.y, wv.y, acc1.y);
            acc1.z = fmaf(av.y, wv.z, acc1.z);
            acc1.w = fmaf(av.y, wv.w, acc1.w);
            acc2.x = fmaf(av.z, wv.x, acc2.x);
            acc2.y = fmaf(av.z, wv.y, acc2.y);
            acc2.z = fmaf(av.z, wv.z, acc2.z);
            acc2.w = fmaf(av.z, wv.w, acc2.w);
            acc3.x = fmaf(av.w, wv.x, acc3.x);
            acc3.y = fmaf(av.w, wv.y, acc3.y);
            acc3.z = fmaf(av.w, wv.z, acc3.z);
            acc3.w = fmaf(av.w, wv.w, acc3.w);
        }
        __syncthreads();
    }

#pragma unroll
    for (int j = 0; j < 4; ++j) {
        int row = gn0 + n0 + j;
        if (row < N) {
            float4 v = (j == 0) ? acc0 : (j == 1) ? acc1 : (j == 2) ? acc2 : acc3;
            *(float4*)(kan + (size_t)row * 128 + o0) = v;
        }
    }
}

// ---------- per-node attention scores: s_src = h.wa1, s_dst = h.wa2 ----------
__global__ __launch_bounds__(256) void k_scores(const float* __restrict__ h,
                                                const float* __restrict__ wa,
                                                float* __restrict__ s_src,
                                                float* __restrict__ s_dst, int N) {
    int wid = (blockIdx.x * 256 + threadIdx.x) >> 6;
    int lane = threadIdx.x & 63;
    if (wid >= N) return;
    const float* hr = h + (size_t)wid * 128;
    float x0 = hr[lane], x1 = hr[64 + lane];
    float s1 = x0 * wa[lane] + x1 * wa[64 + lane];
    float s2 = x0 * wa[128 + lane] + x1 * wa[192 + lane];
#pragma unroll
    for (int off = 32; off; off >>= 1) {
        s1 += __shfl_xor(s1, off, 64);
        s2 += __shfl_xor(s2, off, 64);
    }
    if (lane == 0) {
        s_src[wid] = s1;
        s_dst[wid] = s2;
    }
}

// ---------- CSR build ----------
__global__ void k_hist(const int* __restrict__ row, int* __restrict__ counts, int E) {
    int e = blockIdx.x * 256 + threadIdx.x;
    if (e < E) atomicAdd(&counts[row[e]], 1);
}

__global__ __launch_bounds__(1024) void k_scan(const int* __restrict__ counts,
                                               int* __restrict__ offsets, int N) {
    __shared__ int buf[1024];
    __shared__ int carry_s;
    int tid = threadIdx.x;
    if (tid == 0) carry_s = 0;
    __syncthreads();
    for (int base = 0; base < N; base += 1024) {
        int idx = base + tid;
        int v = (idx < N) ? counts[idx] : 0;
        buf[tid] = v;
        __syncthreads();
        for (int off = 1; off < 1024; off <<= 1) {
            int add = (tid >= off) ? buf[tid - off] : 0;
            __syncthreads();
            buf[tid] += add;
            __syncthreads();
        }
        int incl = buf[tid];
        int carry = carry_s;
        if (idx < N) offsets[idx] = carry + incl - v;  // exclusive
        __syncthreads();
        if (tid == 1023) carry_s = carry + incl;
        __syncthreads();
    }
    if (tid == 0) offsets[N] = carry_s;
}

__global__ void k_scatter(const int* __restrict__ row, const int* __restrict__ col,
                          const int* __restrict__ offsets, int* __restrict__ cursor,
                          int* __restrict__ cols_s, int E) {
    int e = blockIdx.x * 256 + threadIdx.x;
    if (e >= E) return;
    int r = row[e];
    int pos = offsets[r] + atomicAdd(&cursor[r], 1);
    cols_s[pos] = col[e];
}

// ---------- per-row segment softmax + weighted gather-sum (one wave per row) ----------
__global__ __launch_bounds__(256) void k_aggr(const int* __restrict__ offsets,
                                              const int* __restrict__ cols,
                                              const float* __restrict__ s_src,
                                              const float* __restrict__ s_dst,
                                              const float* __restrict__ kan,
                                              float* __restrict__ out, int N) {
    int wid = (blockIdx.x * 256 + threadIdx.x) >> 6;
    int lane = threadIdx.x & 63;
    if (wid >= N) return;
    int start = offsets[wid], end = offsets[wid + 1];
    float acc0 = 0.f, acc1 = 0.f;
    if (end > start) {
        float ssrc = s_src[wid];
        float m = -3.402823466e38f;
        for (int j = start + lane; j < end; j += 64) {
            float e = ssrc + s_dst[cols[j]];
            e = (e >= 0.f) ? e : 0.2f * e;
            m = fmaxf(m, e);
        }
#pragma unroll
        for (int off = 32; off; off >>= 1) m = fmaxf(m, __shfl_xor(m, off, 64));
        float s = 0.f;
        for (int j = start + lane; j < end; j += 64) {
            float e = ssrc + s_dst[cols[j]];
            e = (e >= 0.f) ? e : 0.2f * e;
            s += __expf(e - m);
        }
#pragma unroll
        for (int off = 32; off; off >>= 1) s += __shfl_xor(s, off, 64);
        float inv = 1.0f / s;
        for (int j = start; j < end; ++j) {
            int c = cols[j];  // wave-uniform -> broadcast load
            float e = ssrc + s_dst[c];
            e = (e >= 0.f) ? e : 0.2f * e;
            float att = __expf(e - m) * inv;
            const float* kr = kan + (size_t)c * 128;
            acc0 = fmaf(att, kr[lane], acc0);
            acc1 = fmaf(att, kr[64 + lane], acc1);
        }
    }
    out[(size_t)wid * 128 + lane] = acc0;
    out[(size_t)wid * 128 + 64 + lane] = acc1;
}

extern "C" void kernel_launch(void* const* d_in, const int* in_sizes, int n_in,
                              void* d_out, int out_size, void* d_ws, size_t ws_size,
                              hipStream_t stream) {
    const float* h  = (const float*)d_in[0];
    const int*   ei = (const int*)d_in[1];
    const float* W  = (const float*)d_in[2];
    const float* a  = (const float*)d_in[3];
    const float* bw = (const float*)d_in[4];
    const float* sw = (const float*)d_in[5];
    float* out = (float*)d_out;
    const int N = in_sizes[0] / 128;
    const int E = in_sizes[1] / 2;

    char* ws = (char*)d_ws;
    auto alloc = [&](size_t bytes) {
        char* p = ws;
        ws += (bytes + 255) & ~(size_t)255;
        return p;
    };
    float* Bt    = (float*)alloc((size_t)KTOT * 128 * 4);
    float* wa    = (float*)alloc(256 * 4);
    float* ssrc  = (float*)alloc((size_t)N * 4);
    float* sdst  = (float*)alloc((size_t)N * 4);
    float* kan   = (float*)alloc((size_t)N * 128 * 4);
    int* counts  = (int*)alloc((size_t)N * 4);
    int* cursor  = (int*)alloc((size_t)N * 4);
    int* offsets = (int*)alloc(((size_t)N + 1) * 4);
    int* colss   = (int*)alloc((size_t)E * 4);

    hipMemsetAsync(counts, 0, (size_t)N * 4, stream);
    hipMemsetAsync(cursor, 0, (size_t)N * 4, stream);

    k_prep<<<(KTOT * 128 + 255) / 256, 256, 0, stream>>>(bw, sw, Bt);
    k_wa<<<1, 128, 0, stream>>>(W, a, wa);
    k_nodes<<<(N + 31) / 32, 256, 0, stream>>>(h, Bt, kan, N);
    k_scores<<<(N + 3) / 4, 256, 0, stream>>>(h, wa, ssrc, sdst, N);
    k_hist<<<(E + 255) / 256, 256, 0, stream>>>(ei, counts, E);
    k_scan<<<1, 1024, 0, stream>>>(counts, offsets, N);
    k_scatter<<<(E + 255) / 256, 256, 0, stream>>>(ei, ei + E, offsets, cursor, colss, E);
    k_aggr<<<(N + 3) / 4, 256, 0, stream>>>(offsets, colss, ssrc, sdst, kan, out, N);
}

// Round 3
// 430.904 us; speedup vs baseline: 1.2789x; 1.2789x over previous
//
#include <hip/hip_runtime.h>
#include <hip/hip_bf16.h>
#include <math.h>

#define KTOT 1152   // 128 (silu base) + 1024 (128 features x 8 spline bases)
#define NCHUNK 9
#define BM 64

typedef __attribute__((ext_vector_type(4))) float f32x4;
typedef __attribute__((ext_vector_type(8))) short bf16x8;
typedef unsigned int u32;

__device__ __forceinline__ unsigned short f2bf(float f) {
    u32 u = __builtin_bit_cast(u32, f);
    u32 r = (u + 0x7FFFu + ((u >> 16) & 1u)) >> 16;
    return (unsigned short)r;
}

__device__ __forceinline__ float siluf(float x) {
    return x / (1.0f + __expf(-x));
}

// cubic B-spline bases on the fixed uniform grid (GRID_SIZE=5, order=3)
__device__ __forceinline__ void bspline8(float x, float* out) {
    float g[12];
#pragma unroll
    for (int i = 0; i < 12; ++i) g[i] = (float)(i - 3) * 0.4f - 1.0f;
    float b[11];
#pragma unroll
    for (int i = 0; i < 11; ++i) b[i] = (x >= g[i] && x < g[i + 1]) ? 1.0f : 0.0f;
#pragma unroll
    for (int k = 1; k <= 3; ++k) {
#pragma unroll
        for (int i = 0; i + k < 11; ++i) {
            float left  = (x - g[i]) * (1.0f / (g[i + k] - g[i]));
            float right = (g[i + k + 1] - x) * (1.0f / (g[i + k + 1] - g[i + 1]));
            b[i] = left * b[i] + right * b[i + 1];
        }
    }
#pragma unroll
    for (int c = 0; c < 8; ++c) out[c] = b[c];
}

// ---------- wa = W @ a halves ----------
__global__ void k_wa(const float* __restrict__ W, const float* __restrict__ a,
                     float* __restrict__ wa) {
    int fi = threadIdx.x;  // 128 threads
    float s1 = 0.f, s2 = 0.f;
    for (int o = 0; o < 128; ++o) {
        float w = W[fi * 128 + o];
        s1 = fmaf(w, a[o], s1);
        s2 = fmaf(w, a[128 + o], s2);
    }
    wa[fi] = s1;
    wa[128 + fi] = s2;
}

// ---------- pre-swizzled bf16 weight image ----------
// Bsw element index i = ((c*128 + o)*16 + s)*8 + j holds B[o][c*128 + (s^(o&7))*8 + j]
// where B[o][k] = k<128 ? base_weight[o][k] : spline_weight[o][k-128].
// Linear global_load_lds of a chunk then produces the XOR-swizzled LDS image.
__global__ void k_prep(const float* __restrict__ bw, const float* __restrict__ sw,
                       unsigned short* __restrict__ Bsw) {
    int i = blockIdx.x * 256 + threadIdx.x;
    if (i >= NCHUNK * 128 * 128) return;
    int j = i & 7;
    int s = (i >> 3) & 15;
    int o = (i >> 7) & 127;
    int c = i >> 14;
    int k = c * 128 + (((s ^ (o & 7)) << 3) | j);
    float v = (k < 128) ? bw[o * 128 + k] : sw[o * 1024 + (k - 128)];
    Bsw[i] = f2bf(v);
}

// ---------- main node kernel: bf16 MFMA GEMM with on-the-fly A generation ----------
__global__ __launch_bounds__(256) void k_nodes(const float* __restrict__ h,
                                               const unsigned short* __restrict__ Bsw,
                                               float* __restrict__ kan, int N) {
    __shared__ float h_lds[BM][128];            // 32 KB
    __shared__ unsigned short A_lds[BM * 128];  // 16 KB, XOR-swizzled
    __shared__ unsigned short B_lds[128 * 128]; // 32 KB, XOR-swizzled (pre-swz global)
    const int tid = threadIdx.x;
    const int wid = tid >> 6, lane = tid & 63;
    const int gm0 = blockIdx.x * BM;

    // load h tile, float4-vectorized
    for (int i = tid; i < BM * 32; i += 256) {
        int m = i >> 5, q = i & 31;
        int row = gm0 + m;
        if (row >= N) row = N - 1;
        ((float4*)h_lds[m])[q] = ((const float4*)(h + (size_t)row * 128))[q];
    }
    __syncthreads();  // h_lds visible to all threads before A generation (race fix)

    const int wm0 = (wid >> 1) * 32;  // wave row offset within tile
    const int wn0 = (wid & 1) * 64;   // wave col offset
    f32x4 acc[2][4];
#pragma unroll
    for (int im = 0; im < 2; ++im)
#pragma unroll
        for (int in = 0; in < 4; ++in) acc[im][in] = {0.f, 0.f, 0.f, 0.f};

    for (int chunk = 0; chunk < NCHUNK; ++chunk) {
        // async-stage B chunk (32 KB): each wave copies its 8 KB segment, 8x 1KB issues
        {
            const char* gsrc = (const char*)Bsw + (size_t)chunk * 32768 + wid * 8192 + lane * 16;
            char* ldst = (char*)B_lds + wid * 8192;
#pragma unroll
            for (int i = 0; i < 8; ++i) {
                __builtin_amdgcn_global_load_lds(
                    (const __attribute__((address_space(1))) u32*)(gsrc + i * 1024),
                    (__attribute__((address_space(3))) u32*)(ldst + i * 1024), 16, 0, 0);
            }
        }
        // generate A chunk into swizzled LDS (bf16)
        if (chunk == 0) {
            for (int b = tid; b < BM * 16; b += 256) {
                int m = b >> 4, s = b & 15;
                unsigned short pk[8];
#pragma unroll
                for (int j = 0; j < 8; ++j) pk[j] = f2bf(siluf(h_lds[m][s * 8 + j]));
                *(bf16x8*)((char*)A_lds + m * 256 + (((s ^ (m & 7)) & 15) << 4)) =
                    *(bf16x8*)pk;
            }
        } else {
            int fb = (chunk - 1) * 16;
            for (int b = tid; b < BM * 16; b += 256) {
                int m = b >> 4, f = b & 15;
                float bas[8];
                bspline8(h_lds[m][fb + f], bas);
                unsigned short pk[8];
#pragma unroll
                for (int j = 0; j < 8; ++j) pk[j] = f2bf(bas[j]);
                *(bf16x8*)((char*)A_lds + m * 256 + (((f ^ (m & 7)) & 15) << 4)) =
                    *(bf16x8*)pk;
            }
        }
        __syncthreads();  // drains vmcnt (global_load_lds) + lgkm (ds_write)

        // MFMA: 4 k-steps of 32, 2x4 fragments per wave
#pragma unroll
        for (int kk = 0; kk < 4; ++kk) {
            bf16x8 af[2], bfr[4];
#pragma unroll
            for (int im = 0; im < 2; ++im) {
                int mrow = wm0 + im * 16 + (lane & 15);
                int slot = (kk * 4 + (lane >> 4)) ^ (mrow & 7);
                af[im] = *(const bf16x8*)((const char*)A_lds + mrow * 256 + slot * 16);
            }
#pragma unroll
            for (int in = 0; in < 4; ++in) {
                int orow = wn0 + in * 16 + (lane & 15);
                int slot = (kk * 4 + (lane >> 4)) ^ (orow & 7);
                bfr[in] = *(const bf16x8*)((const char*)B_lds + orow * 256 + slot * 16);
            }
#pragma unroll
            for (int im = 0; im < 2; ++im)
#pragma unroll
                for (int in = 0; in < 4; ++in)
                    acc[im][in] = __builtin_amdgcn_mfma_f32_16x16x32_bf16(
                        af[im], bfr[in], acc[im][in], 0, 0, 0);
        }
        __syncthreads();
    }

    // epilogue: C layout col=lane&15, row=(lane>>4)*4+r
#pragma unroll
    for (int im = 0; im < 2; ++im) {
        int mbase = gm0 + wm0 + im * 16 + ((lane >> 4) << 2);
#pragma unroll
        for (int in = 0; in < 4; ++in) {
            int o = wn0 + in * 16 + (lane & 15);
#pragma unroll
            for (int r = 0; r < 4; ++r) {
                int m = mbase + r;
                if (m < N) kan[(size_t)m * 128 + o] = acc[im][in][r];
            }
        }
    }
}

// ---------- per-node attention scores ----------
__global__ __launch_bounds__(256) void k_scores(const float* __restrict__ h,
                                                const float* __restrict__ wa,
                                                float* __restrict__ s_src,
                                                float* __restrict__ s_dst, int N) {
    int wid = (blockIdx.x * 256 + threadIdx.x) >> 6;
    int lane = threadIdx.x & 63;
    if (wid >= N) return;
    const float* hr = h + (size_t)wid * 128;
    float x0 = hr[lane], x1 = hr[64 + lane];
    float s1 = x0 * wa[lane] + x1 * wa[64 + lane];
    float s2 = x0 * wa[128 + lane] + x1 * wa[192 + lane];
#pragma unroll
    for (int off = 32; off; off >>= 1) {
        s1 += __shfl_xor(s1, off, 64);
        s2 += __shfl_xor(s2, off, 64);
    }
    if (lane == 0) {
        s_src[wid] = s1;
        s_dst[wid] = s2;
    }
}

// ---------- CSR build ----------
__global__ void k_hist(const int* __restrict__ row, int* __restrict__ counts, int E) {
    int e = blockIdx.x * 256 + threadIdx.x;
    if (e < E) atomicAdd(&counts[row[e]], 1);
}

// 3-phase single-block scan: serial thread chunks + wave shuffle scan (2 barriers)
__global__ __launch_bounds__(1024) void k_scan(const int* __restrict__ counts,
                                               int* __restrict__ offsets, int N) {
    __shared__ int wsum[16];
    __shared__ int total_s;
    int tid = threadIdx.x;
    int chunk = (N + 1023) / 1024;
    int start = tid * chunk;
    int end = start + chunk;
    if (end > N) end = N;
    int s = 0;
    for (int i = start; i < end; ++i) s += counts[i];
    int lane = tid & 63, w = tid >> 6;
    int v = s;
#pragma unroll
    for (int off = 1; off < 64; off <<= 1) {
        int t = __shfl_up(v, off, 64);
        if (lane >= off) v += t;
    }
    if (lane == 63) wsum[w] = v;
    __syncthreads();
    if (w == 0 && lane < 16) {
        int x = wsum[lane];
#pragma unroll
        for (int off = 1; off < 16; off <<= 1) {
            int t = __shfl_up(x, off, 64);
            if (lane >= off) x += t;
        }
        wsum[lane] = x;
        if (lane == 15) total_s = x;
    }
    __syncthreads();
    int wbase = (w > 0) ? wsum[w - 1] : 0;
    int tbase = wbase + v - s;  // exclusive prefix of this thread's chunk
    for (int i = start; i < end; ++i) {
        int c = counts[i];
        offsets[i] = tbase;
        tbase += c;
    }
    if (tid == 0) offsets[N] = total_s;
}

__global__ void k_scatter(const int* __restrict__ row, const int* __restrict__ col,
                          const int* __restrict__ offsets, int* __restrict__ cursor,
                          int* __restrict__ cols_s, int E) {
    int e = blockIdx.x * 256 + threadIdx.x;
    if (e >= E) return;
    int r = row[e];
    int pos = offsets[r] + atomicAdd(&cursor[r], 1);
    cols_s[pos] = col[e];
}

// sort each row's cols ascending (one thread per row, insertion sort; avg deg 16).
// Makes within-row order — and hence fp summation order — deterministic across
// calls regardless of the atomicAdd order in k_scatter. Duplicate col values
// yield bitwise-identical terms, so sorted order fixes the sum bitwise.
__global__ void k_sortrows(const int* __restrict__ offsets, int* __restrict__ cols, int N) {
    int r = blockIdx.x * 256 + threadIdx.x;
    if (r >= N) return;
    int s = offsets[r], e = offsets[r + 1];
    for (int i = s + 1; i < e; ++i) {
        int v = cols[i];
        int j = i - 1;
        while (j >= s && cols[j] > v) { cols[j + 1] = cols[j]; --j; }
        cols[j + 1] = v;
    }
}

// ---------- per-row segment softmax + weighted gather-sum ----------
__global__ __launch_bounds__(256) void k_aggr(const int* __restrict__ offsets,
                                              const int* __restrict__ cols,
                                              const float* __restrict__ s_src,
                                              const float* __restrict__ s_dst,
                                              const float* __restrict__ kan,
                                              float* __restrict__ out, int N) {
    int wid = (blockIdx.x * 256 + threadIdx.x) >> 6;
    int lane = threadIdx.x & 63;
    if (wid >= N) return;
    int start = offsets[wid], end = offsets[wid + 1];
    float acc0 = 0.f, acc1 = 0.f;
    if (end > start) {
        float ssrc = s_src[wid];
        float m = -3.402823466e38f;
        for (int j = start + lane; j < end; j += 64) {
            float e = ssrc + s_dst[cols[j]];
            e = (e >= 0.f) ? e : 0.2f * e;
            m = fmaxf(m, e);
        }
#pragma unroll
        for (int off = 32; off; off >>= 1) m = fmaxf(m, __shfl_xor(m, off, 64));
        float s = 0.f;
        for (int j = start + lane; j < end; j += 64) {
            float e = ssrc + s_dst[cols[j]];
            e = (e >= 0.f) ? e : 0.2f * e;
            s += __expf(e - m);
        }
#pragma unroll
        for (int off = 32; off; off >>= 1) s += __shfl_xor(s, off, 64);
        float inv = 1.0f / s;
        for (int j = start; j < end; ++j) {
            int c = cols[j];  // wave-uniform -> broadcast load
            float e = ssrc + s_dst[c];
            e = (e >= 0.f) ? e : 0.2f * e;
            float att = __expf(e - m) * inv;
            const float* kr = kan + (size_t)c * 128;
            acc0 = fmaf(att, kr[lane], acc0);
            acc1 = fmaf(att, kr[64 + lane], acc1);
        }
    }
    out[(size_t)wid * 128 + lane] = acc0;
    out[(size_t)wid * 128 + 64 + lane] = acc1;
}

extern "C" void kernel_launch(void* const* d_in, const int* in_sizes, int n_in,
                              void* d_out, int out_size, void* d_ws, size_t ws_size,
                              hipStream_t stream) {
    const float* h  = (const float*)d_in[0];
    const int*   ei = (const int*)d_in[1];
    const float* W  = (const float*)d_in[2];
    const float* a  = (const float*)d_in[3];
    const float* bw = (const float*)d_in[4];
    const float* sw = (const float*)d_in[5];
    float* out = (float*)d_out;
    const int N = in_sizes[0] / 128;
    const int E = in_sizes[1] / 2;

    char* ws = (char*)d_ws;
    auto alloc = [&](size_t bytes) {
        char* p = ws;
        ws += (bytes + 255) & ~(size_t)255;
        return p;
    };
    unsigned short* Bsw = (unsigned short*)alloc((size_t)KTOT * 128 * 2);
    float* wa    = (float*)alloc(256 * 4);
    float* ssrc  = (float*)alloc((size_t)N * 4);
    float* sdst  = (float*)alloc((size_t)N * 4);
    float* kan   = (float*)alloc((size_t)N * 128 * 4);
    int* counts  = (int*)alloc((size_t)N * 4);
    int* cursor  = (int*)alloc((size_t)N * 4);
    int* offsets = (int*)alloc(((size_t)N + 1) * 4);
    int* colss   = (int*)alloc((size_t)E * 4);

    hipMemsetAsync(counts, 0, (size_t)N * 4, stream);
    hipMemsetAsync(cursor, 0, (size_t)N * 4, stream);

    k_prep<<<(NCHUNK * 128 * 128 + 255) / 256, 256, 0, stream>>>(bw, sw, Bsw);
    k_wa<<<1, 128, 0, stream>>>(W, a, wa);
    k_nodes<<<(N + BM - 1) / BM, 256, 0, stream>>>(h, Bsw, kan, N);
    k_scores<<<(N + 3) / 4, 256, 0, stream>>>(h, wa, ssrc, sdst, N);
    k_hist<<<(E + 255) / 256, 256, 0, stream>>>(ei, counts, E);
    k_scan<<<1, 1024, 0, stream>>>(counts, offsets, N);
    k_scatter<<<(E + 255) / 256, 256, 0, stream>>>(ei, ei + E, offsets, cursor, colss, E);
    k_sortrows<<<(N + 255) / 256, 256, 0, stream>>>(offsets, colss, N);
    k_aggr<<<(N + 3) / 4, 256, 0, stream>>>(offsets, colss, ssrc, sdst, kan, out, N);
}

// Round 4
// 339.743 us; speedup vs baseline: 1.6221x; 1.2683x over previous
//
#include <hip/hip_runtime.h>
#include <hip/hip_bf16.h>
#include <math.h>

#define KTOT 1152   // 128 (silu base) + 1024 (128 features x 8 spline bases)
#define NCHUNK 9
#define BM 64

typedef __attribute__((ext_vector_type(4))) float f32x4;
typedef __attribute__((ext_vector_type(8))) short bf16x8;
typedef unsigned int u32;

__device__ __forceinline__ unsigned short f2bf(float f) {
    u32 u = __builtin_bit_cast(u32, f);
    u32 r = (u + 0x7FFFu + ((u >> 16) & 1u)) >> 16;
    return (unsigned short)r;
}

__device__ __forceinline__ float siluf(float x) {
    return x / (1.0f + __expf(-x));
}

// cubic B-spline bases on the fixed uniform grid (GRID_SIZE=5, order=3)
__device__ __forceinline__ void bspline8(float x, float* out) {
    float g[12];
#pragma unroll
    for (int i = 0; i < 12; ++i) g[i] = (float)(i - 3) * 0.4f - 1.0f;
    float b[11];
#pragma unroll
    for (int i = 0; i < 11; ++i) b[i] = (x >= g[i] && x < g[i + 1]) ? 1.0f : 0.0f;
#pragma unroll
    for (int k = 1; k <= 3; ++k) {
#pragma unroll
        for (int i = 0; i + k < 11; ++i) {
            float left  = (x - g[i]) * (1.0f / (g[i + k] - g[i]));
            float right = (g[i + k + 1] - x) * (1.0f / (g[i + k + 1] - g[i + 1]));
            b[i] = left * b[i] + right * b[i + 1];
        }
    }
#pragma unroll
    for (int c = 0; c < 8; ++c) out[c] = b[c];
}

// ---------- wa = W @ a halves ----------
__global__ void k_wa(const float* __restrict__ W, const float* __restrict__ a,
                     float* __restrict__ wa) {
    int fi = threadIdx.x;  // 128 threads
    float s1 = 0.f, s2 = 0.f;
    for (int o = 0; o < 128; ++o) {
        float w = W[fi * 128 + o];
        s1 = fmaf(w, a[o], s1);
        s2 = fmaf(w, a[128 + o], s2);
    }
    wa[fi] = s1;
    wa[128 + fi] = s2;
}

// ---------- pre-swizzled bf16 weight image (see round-1 comment) ----------
__global__ void k_prep(const float* __restrict__ bw, const float* __restrict__ sw,
                       unsigned short* __restrict__ Bsw) {
    int i = blockIdx.x * 256 + threadIdx.x;
    if (i >= NCHUNK * 128 * 128) return;
    int j = i & 7;
    int s = (i >> 3) & 15;
    int o = (i >> 7) & 127;
    int c = i >> 14;
    int k = c * 128 + (((s ^ (o & 7)) << 3) | j);
    float v = (k < 128) ? bw[o * 128 + k] : sw[o * 1024 + (k - 128)];
    Bsw[i] = f2bf(v);
}

// ---------- main node kernel: bf16 MFMA GEMM + fused attention scores ----------
__global__ __launch_bounds__(256) void k_nodes(const float* __restrict__ h,
                                               const unsigned short* __restrict__ Bsw,
                                               const float* __restrict__ wa,
                                               unsigned short* __restrict__ kanb,
                                               float* __restrict__ s_src,
                                               float* __restrict__ s_dst, int N) {
    __shared__ float h_lds[BM][128];            // 32 KB
    __shared__ unsigned short A_lds[BM * 128];  // 16 KB, XOR-swizzled (reused for C out)
    __shared__ unsigned short B_lds[128 * 128]; // 32 KB, XOR-swizzled (pre-swz global)
    const int tid = threadIdx.x;
    const int wid = tid >> 6, lane = tid & 63;
    const int gm0 = blockIdx.x * BM;

    // load h tile, float4-vectorized
    for (int i = tid; i < BM * 32; i += 256) {
        int m = i >> 5, q = i & 31;
        int row = gm0 + m;
        if (row >= N) row = N - 1;
        ((float4*)h_lds[m])[q] = ((const float4*)(h + (size_t)row * 128))[q];
    }
    __syncthreads();  // h_lds visible to all threads

    // fused scores: wave w handles rows w*16..w*16+15 of the tile
    {
        float wa0 = wa[lane], wa1 = wa[64 + lane];
        float wa2 = wa[128 + lane], wa3 = wa[192 + lane];
        for (int rr = 0; rr < 16; ++rr) {
            int m = wid * 16 + rr;
            float x0 = h_lds[m][lane], x1 = h_lds[m][64 + lane];
            float s1 = fmaf(x0, wa0, x1 * wa1);
            float s2 = fmaf(x0, wa2, x1 * wa3);
#pragma unroll
            for (int off = 32; off; off >>= 1) {
                s1 += __shfl_xor(s1, off, 64);
                s2 += __shfl_xor(s2, off, 64);
            }
            int grow = gm0 + m;
            if (lane == 0 && grow < N) {
                s_src[grow] = s1;
                s_dst[grow] = s2;
            }
        }
    }

    const int wm0 = (wid >> 1) * 32;  // wave row offset within tile
    const int wn0 = (wid & 1) * 64;   // wave col offset
    f32x4 acc[2][4];
#pragma unroll
    for (int im = 0; im < 2; ++im)
#pragma unroll
        for (int in = 0; in < 4; ++in) acc[im][in] = {0.f, 0.f, 0.f, 0.f};

    for (int chunk = 0; chunk < NCHUNK; ++chunk) {
        // async-stage B chunk (32 KB): each wave copies its 8 KB segment
        {
            const char* gsrc = (const char*)Bsw + (size_t)chunk * 32768 + wid * 8192 + lane * 16;
            char* ldst = (char*)B_lds + wid * 8192;
#pragma unroll
            for (int i = 0; i < 8; ++i) {
                __builtin_amdgcn_global_load_lds(
                    (const __attribute__((address_space(1))) u32*)(gsrc + i * 1024),
                    (__attribute__((address_space(3))) u32*)(ldst + i * 1024), 16, 0, 0);
            }
        }
        // generate A chunk into swizzled LDS (bf16)
        if (chunk == 0) {
            for (int b = tid; b < BM * 16; b += 256) {
                int m = b >> 4, s = b & 15;
                unsigned short pk[8];
#pragma unroll
                for (int j = 0; j < 8; ++j) pk[j] = f2bf(siluf(h_lds[m][s * 8 + j]));
                *(bf16x8*)((char*)A_lds + m * 256 + (((s ^ (m & 7)) & 15) << 4)) =
                    *(bf16x8*)pk;
            }
        } else {
            int fb = (chunk - 1) * 16;
            for (int b = tid; b < BM * 16; b += 256) {
                int m = b >> 4, f = b & 15;
                float bas[8];
                bspline8(h_lds[m][fb + f], bas);
                unsigned short pk[8];
#pragma unroll
                for (int j = 0; j < 8; ++j) pk[j] = f2bf(bas[j]);
                *(bf16x8*)((char*)A_lds + m * 256 + (((f ^ (m & 7)) & 15) << 4)) =
                    *(bf16x8*)pk;
            }
        }
        __syncthreads();  // drains vmcnt (global_load_lds) + lgkm (ds_write)

        // MFMA: 4 k-steps of 32, 2x4 fragments per wave
#pragma unroll
        for (int kk = 0; kk < 4; ++kk) {
            bf16x8 af[2], bfr[4];
#pragma unroll
            for (int im = 0; im < 2; ++im) {
                int mrow = wm0 + im * 16 + (lane & 15);
                int slot = (kk * 4 + (lane >> 4)) ^ (mrow & 7);
                af[im] = *(const bf16x8*)((const char*)A_lds + mrow * 256 + slot * 16);
            }
#pragma unroll
            for (int in = 0; in < 4; ++in) {
                int orow = wn0 + in * 16 + (lane & 15);
                int slot = (kk * 4 + (lane >> 4)) ^ (orow & 7);
                bfr[in] = *(const bf16x8*)((const char*)B_lds + orow * 256 + slot * 16);
            }
#pragma unroll
            for (int im = 0; im < 2; ++im)
#pragma unroll
                for (int in = 0; in < 4; ++in)
                    acc[im][in] = __builtin_amdgcn_mfma_f32_16x16x32_bf16(
                        af[im], bfr[in], acc[im][in], 0, 0, 0);
        }
        __syncthreads();
    }

    // epilogue: acc -> bf16 via LDS (reuse A_lds), then vectorized global store.
    // C layout per frag: col=lane&15, row=(lane>>4)*4+r
#pragma unroll
    for (int im = 0; im < 2; ++im) {
        int rbase = wm0 + im * 16 + ((lane >> 4) << 2);
#pragma unroll
        for (int in = 0; in < 4; ++in) {
            int col = wn0 + in * 16 + (lane & 15);
#pragma unroll
            for (int r = 0; r < 4; ++r) {
                int row = rbase + r;
                int byte = row * 256 + ((col * 2) ^ ((row & 7) << 4));
                *(unsigned short*)((char*)A_lds + byte) = f2bf(acc[im][in][r]);
            }
        }
    }
    __syncthreads();
    for (int i = tid; i < BM * 16; i += 256) {
        int row = i >> 4, s = i & 15;
        int byte = row * 256 + ((s << 4) ^ ((row & 7) << 4));
        bf16x8 v = *(bf16x8*)((char*)A_lds + byte);
        int grow = gm0 + row;
        if (grow < N) *(bf16x8*)((char*)kanb + (size_t)grow * 256 + s * 16) = v;
    }
}

// ---------- CSR build ----------
__global__ void k_hist(const int* __restrict__ row, int* __restrict__ counts, int E) {
    int e = blockIdx.x * 256 + threadIdx.x;
    if (e < E) atomicAdd(&counts[row[e]], 1);
}

// 3-kernel coalesced scan: block sums -> block scan -> offsets
__global__ void k_scan1(const int* __restrict__ counts, int* __restrict__ bsum, int N) {
    int tid = threadIdx.x;
    int idx = blockIdx.x * 256 + tid;
    int v = (idx < N) ? counts[idx] : 0;
#pragma unroll
    for (int off = 32; off; off >>= 1) v += __shfl_xor(v, off, 64);
    __shared__ int ws[4];
    if ((tid & 63) == 0) ws[tid >> 6] = v;
    __syncthreads();
    if (tid == 0) bsum[blockIdx.x] = ws[0] + ws[1] + ws[2] + ws[3];
}

__global__ __launch_bounds__(1024) void k_scan2(const int* __restrict__ bsum,
                                                int* __restrict__ ebase,
                                                int* __restrict__ offsN, int nb) {
    __shared__ int ws[16];
    __shared__ int tot;
    int tid = threadIdx.x;
    int lane = tid & 63, w = tid >> 6;
    int v = (tid < nb) ? bsum[tid] : 0;
    int inc = v;
#pragma unroll
    for (int off = 1; off < 64; off <<= 1) {
        int t = __shfl_up(inc, off, 64);
        if (lane >= off) inc += t;
    }
    if (lane == 63) ws[w] = inc;
    __syncthreads();
    if (w == 0 && lane < 16) {
        int x = ws[lane];
#pragma unroll
        for (int off = 1; off < 16; off <<= 1) {
            int t = __shfl_up(x, off, 64);
            if (lane >= off) x += t;
        }
        ws[lane] = x;
        if (lane == 15) tot = x;
    }
    __syncthreads();
    int wb = w ? ws[w - 1] : 0;
    if (tid < nb) ebase[tid] = wb + inc - v;  // exclusive
    if (tid == 0) offsN[0] = tot;
}

__global__ void k_scan3(const int* __restrict__ counts, const int* __restrict__ ebase,
                        int* __restrict__ offsets, int N) {
    int tid = threadIdx.x;
    int idx = blockIdx.x * 256 + tid;
    int v = (idx < N) ? counts[idx] : 0;
    int lane = tid & 63, w = tid >> 6;
    int inc = v;
#pragma unroll
    for (int off = 1; off < 64; off <<= 1) {
        int t = __shfl_up(inc, off, 64);
        if (lane >= off) inc += t;
    }
    __shared__ int ws[4];
    if (lane == 63) ws[w] = inc;
    __syncthreads();
    int wb = 0;
    for (int i = 0; i < w; ++i) wb += ws[i];
    if (idx < N) offsets[idx] = ebase[blockIdx.x] + wb + inc - v;
}

__global__ void k_scatter(const int* __restrict__ row, const int* __restrict__ col,
                          const int* __restrict__ offsets, int* __restrict__ cursor,
                          int* __restrict__ cols_s, int E) {
    int e = blockIdx.x * 256 + threadIdx.x;
    if (e >= E) return;
    int r = row[e];
    int pos = offsets[r] + atomicAdd(&cursor[r], 1);
    cols_s[pos] = col[e];
}

// sort each row's cols ascending -> deterministic fp summation order
__global__ void k_sortrows(const int* __restrict__ offsets, int* __restrict__ cols, int N) {
    int r = blockIdx.x * 256 + threadIdx.x;
    if (r >= N) return;
    int s = offsets[r], e = offsets[r + 1];
    for (int i = s + 1; i < e; ++i) {
        int v = cols[i];
        int j = i - 1;
        while (j >= s && cols[j] > v) { cols[j + 1] = cols[j]; --j; }
        cols[j + 1] = v;
    }
}

// ---------- per-row segment softmax + weighted bf16 gather-sum ----------
__global__ __launch_bounds__(256) void k_aggr(const int* __restrict__ offsets,
                                              const int* __restrict__ cols,
                                              const float* __restrict__ s_src,
                                              const float* __restrict__ s_dst,
                                              const unsigned short* __restrict__ kanb,
                                              float* __restrict__ out, int N) {
    int wid = (blockIdx.x * 256 + threadIdx.x) >> 6;
    int lane = threadIdx.x & 63;
    if (wid >= N) return;
    int start = offsets[wid], end = offsets[wid + 1];
    float acc0 = 0.f, acc1 = 0.f;
    if (end > start) {
        float ssrc = s_src[wid];
        float m = -3.402823466e38f;
        for (int j = start + lane; j < end; j += 64) {
            float e = ssrc + s_dst[cols[j]];
            e = (e >= 0.f) ? e : 0.2f * e;
            m = fmaxf(m, e);
        }
#pragma unroll
        for (int off = 32; off; off >>= 1) m = fmaxf(m, __shfl_xor(m, off, 64));
        float s = 0.f;
        for (int j = start + lane; j < end; j += 64) {
            float e = ssrc + s_dst[cols[j]];
            e = (e >= 0.f) ? e : 0.2f * e;
            s += __expf(e - m);
        }
#pragma unroll
        for (int off = 32; off; off >>= 1) s += __shfl_xor(s, off, 64);
        float inv = 1.0f / s;
        // chunk of 64 edges: lane computes its own att once, then broadcast
        for (int t = start; t < end; t += 64) {
            int j = t + lane;
            float att = 0.f;
            int myc = 0;
            if (j < end) {
                myc = cols[j];
                float e = ssrc + s_dst[myc];
                e = (e >= 0.f) ? e : 0.2f * e;
                att = __expf(e - m) * inv;
            }
            int cnt = min(64, end - t);
            for (int q = 0; q < cnt; ++q) {
                float w = __shfl(att, q, 64);
                int c = __shfl(myc, q, 64);
                u32 p = ((const u32*)(kanb + (size_t)c * 128))[lane];
                float lo = __builtin_bit_cast(float, p << 16);
                float hi = __builtin_bit_cast(float, p & 0xffff0000u);
                acc0 = fmaf(w, lo, acc0);
                acc1 = fmaf(w, hi, acc1);
            }
        }
    }
    // lane covers cols 2*lane (acc0) and 2*lane+1 (acc1)
    float2 o2 = make_float2(acc0, acc1);
    *(float2*)(out + (size_t)wid * 128 + lane * 2) = o2;
}

extern "C" void kernel_launch(void* const* d_in, const int* in_sizes, int n_in,
                              void* d_out, int out_size, void* d_ws, size_t ws_size,
                              hipStream_t stream) {
    const float* h  = (const float*)d_in[0];
    const int*   ei = (const int*)d_in[1];
    const float* W  = (const float*)d_in[2];
    const float* a  = (const float*)d_in[3];
    const float* bw = (const float*)d_in[4];
    const float* sw = (const float*)d_in[5];
    float* out = (float*)d_out;
    const int N = in_sizes[0] / 128;
    const int E = in_sizes[1] / 2;
    const int nb = (N + 255) / 256;

    char* ws = (char*)d_ws;
    auto alloc = [&](size_t bytes) {
        char* p = ws;
        ws += (bytes + 255) & ~(size_t)255;
        return p;
    };
    unsigned short* Bsw = (unsigned short*)alloc((size_t)KTOT * 128 * 2);
    float* wa    = (float*)alloc(256 * 4);
    float* ssrc  = (float*)alloc((size_t)N * 4);
    float* sdst  = (float*)alloc((size_t)N * 4);
    unsigned short* kanb = (unsigned short*)alloc((size_t)N * 128 * 2);
    int* counts  = (int*)alloc((size_t)N * 4);
    int* cursor  = (int*)alloc((size_t)N * 4);
    int* offsets = (int*)alloc(((size_t)N + 1) * 4);
    int* colss   = (int*)alloc((size_t)E * 4);
    int* bsum    = (int*)alloc((size_t)nb * 4);
    int* ebase   = (int*)alloc((size_t)nb * 4);

    hipMemsetAsync(counts, 0, (size_t)N * 4, stream);
    hipMemsetAsync(cursor, 0, (size_t)N * 4, stream);

    k_prep<<<(NCHUNK * 128 * 128 + 255) / 256, 256, 0, stream>>>(bw, sw, Bsw);
    k_wa<<<1, 128, 0, stream>>>(W, a, wa);
    k_nodes<<<(N + BM - 1) / BM, 256, 0, stream>>>(h, Bsw, wa, kanb, ssrc, sdst, N);
    k_hist<<<(E + 255) / 256, 256, 0, stream>>>(ei, counts, E);
    k_scan1<<<nb, 256, 0, stream>>>(counts, bsum, N);
    k_scan2<<<1, 1024, 0, stream>>>(bsum, ebase, offsets + N, nb);
    k_scan3<<<nb, 256, 0, stream>>>(counts, ebase, offsets, N);
    k_scatter<<<(E + 255) / 256, 256, 0, stream>>>(ei, ei + E, offsets, cursor, colss, E);
    k_sortrows<<<(N + 255) / 256, 256, 0, stream>>>(offsets, colss, N);
    k_aggr<<<(N + 3) / 4, 256, 0, stream>>>(offsets, colss, ssrc, sdst, kanb, out, N);
}

// Round 5
// 231.744 us; speedup vs baseline: 2.3780x; 1.4660x over previous
//
#include <hip/hip_runtime.h>
#include <hip/hip_bf16.h>
#include <math.h>

#define KTOT 1152   // 128 (silu base) + 1024 (128 features x 8 spline bases)
#define NCHUNK 9
#define BM 64

typedef __attribute__((ext_vector_type(4))) float f32x4;
typedef __attribute__((ext_vector_type(8))) short bf16x8;
typedef unsigned int u32;
typedef unsigned long long u64;

__device__ __forceinline__ unsigned short f2bf(float f) {
    u32 u = __builtin_bit_cast(u32, f);
    u32 r = (u + 0x7FFFu + ((u >> 16) & 1u)) >> 16;
    return (unsigned short)r;
}

__device__ __forceinline__ float siluf(float x) {
    return x / (1.0f + __expf(-x));
}

// ---------- wa = W @ a halves ----------
__global__ void k_wa(const float* __restrict__ W, const float* __restrict__ a,
                     float* __restrict__ wa) {
    int fi = threadIdx.x;  // 128 threads
    float s1 = 0.f, s2 = 0.f;
    for (int o = 0; o < 128; ++o) {
        float w = W[fi * 128 + o];
        s1 = fmaf(w, a[o], s1);
        s2 = fmaf(w, a[128 + o], s2);
    }
    wa[fi] = s1;
    wa[128 + fi] = s2;
}

// ---------- pre-swizzled bf16 weight image ----------
// Bsw element i = ((c*128 + o)*16 + s)*8 + j holds B[o][c*128 + (s^(o&7))*8 + j]
// where B[o][k] = k<128 ? base_weight[o][k] : spline_weight[o][k-128].
// Linear global_load_lds of a chunk then lands the XOR-swizzled LDS image.
__global__ void k_prep(const float* __restrict__ bw, const float* __restrict__ sw,
                       unsigned short* __restrict__ Bsw) {
    int i = blockIdx.x * 256 + threadIdx.x;
    if (i >= NCHUNK * 128 * 128) return;
    int j = i & 7;
    int s = (i >> 3) & 15;
    int o = (i >> 7) & 127;
    int c = i >> 14;
    int k = c * 128 + (((s ^ (o & 7)) << 3) | j);
    float v = (k < 128) ? bw[o * 128 + k] : sw[o * 1024 + (k - 128)];
    Bsw[i] = f2bf(v);
}

// ---------- main node kernel: bf16 MFMA GEMM + fused attention scores ----------
// LDS: A 16K + B 32K = 48 KB -> 3 blocks/CU. h is read straight from global (L2-hot).
__global__ __launch_bounds__(256) void k_nodes(const float* __restrict__ h,
                                               const unsigned short* __restrict__ Bsw,
                                               const float* __restrict__ wa,
                                               unsigned short* __restrict__ kanb,
                                               float* __restrict__ s_src,
                                               float* __restrict__ s_dst, int N) {
    __shared__ unsigned short A_lds[BM * 128];  // 16 KB, XOR-swizzled (reused for C out)
    __shared__ unsigned short B_lds[128 * 128]; // 32 KB, XOR-swizzled (pre-swz global)
    const int tid = threadIdx.x;
    const int wid = tid >> 6, lane = tid & 63;
    const int gm0 = blockIdx.x * BM;

    // fused scores: wave w handles tile rows w*16..w*16+15
    {
        float wa0 = wa[lane], wa1 = wa[64 + lane];
        float wa2 = wa[128 + lane], wa3 = wa[192 + lane];
        for (int rr = 0; rr < 16; ++rr) {
            int grow = gm0 + wid * 16 + rr;
            const float* hr = h + (size_t)min(grow, N - 1) * 128;
            float x0 = hr[lane], x1 = hr[64 + lane];
            float s1 = fmaf(x0, wa0, x1 * wa1);
            float s2 = fmaf(x0, wa2, x1 * wa3);
#pragma unroll
            for (int off = 32; off; off >>= 1) {
                s1 += __shfl_xor(s1, off, 64);
                s2 += __shfl_xor(s2, off, 64);
            }
            if (lane == 0 && grow < N) {
                s_src[grow] = s1;
                s_dst[grow] = s2;
            }
        }
    }

    const int wm0 = (wid >> 1) * 32;  // wave row offset within tile
    const int wn0 = (wid & 1) * 64;   // wave col offset
    f32x4 acc[2][4];
#pragma unroll
    for (int im = 0; im < 2; ++im)
#pragma unroll
        for (int in = 0; in < 4; ++in) acc[im][in] = {0.f, 0.f, 0.f, 0.f};

    for (int chunk = 0; chunk < NCHUNK; ++chunk) {
        // async-stage B chunk (32 KB): each wave copies its 8 KB segment
        {
            const char* gsrc = (const char*)Bsw + (size_t)chunk * 32768 + wid * 8192 + lane * 16;
            char* ldst = (char*)B_lds + wid * 8192;
#pragma unroll
            for (int i = 0; i < 8; ++i) {
                __builtin_amdgcn_global_load_lds(
                    (const __attribute__((address_space(1))) u32*)(gsrc + i * 1024),
                    (__attribute__((address_space(3))) u32*)(ldst + i * 1024), 16, 0, 0);
            }
        }
        // generate A chunk into swizzled LDS (bf16); hides the B-load latency
        if (chunk == 0) {
            for (int b = tid; b < BM * 16; b += 256) {
                int m = b >> 4, s = b & 15;
                const float* hr = h + (size_t)min(gm0 + m, N - 1) * 128 + s * 8;
                float4 v0 = *(const float4*)hr;
                float4 v1 = *(const float4*)(hr + 4);
                unsigned short pk[8];
                pk[0] = f2bf(siluf(v0.x)); pk[1] = f2bf(siluf(v0.y));
                pk[2] = f2bf(siluf(v0.z)); pk[3] = f2bf(siluf(v0.w));
                pk[4] = f2bf(siluf(v1.x)); pk[5] = f2bf(siluf(v1.y));
                pk[6] = f2bf(siluf(v1.z)); pk[7] = f2bf(siluf(v1.w));
                *(bf16x8*)((char*)A_lds + m * 256 + (((s ^ (m & 7)) & 15) << 4)) =
                    *(bf16x8*)pk;
            }
        } else {
            // closed-form cardinal cubic B-spline on the uniform grid.
            // t = (x+2.2)/0.4; i0 = floor(t); u = frac. Nonzero bases c=i0-3..i0 with
            // weights {(1-u)^3, 3u^3-6u^2+4, -3u^3+3u^2+3u+1, u^3}/6. Out-of-range -> 0.
            int fb = (chunk - 1) * 16;
            for (int b = tid; b < BM * 16; b += 256) {
                int m = b >> 4, f = b & 15;
                float x = h[(size_t)min(gm0 + m, N - 1) * 128 + fb + f];
                float t = (x + 2.2f) * 2.5f;
                float fl = floorf(t);
                int i0 = (int)fl;
                float u = t - fl;
                float um = 1.0f - u;
                float u2 = u * u, u3 = u2 * u;
                const float c6 = 1.0f / 6.0f;
                float w0 = um * um * um * c6;
                float w1 = (3.f * u3 - 6.f * u2 + 4.f) * c6;
                float w2 = (-3.f * u3 + 3.f * u2 + 3.f * u + 1.f) * c6;
                float w3 = u3 * c6;
                u64 W = (u64)f2bf(w0) | ((u64)f2bf(w1) << 16) |
                        ((u64)f2bf(w2) << 32) | ((u64)f2bf(w3) << 48);
                int sh = (i0 - 3) * 16;  // slot j0 = i0-3, 16 bits per bf16 slot
                u64 lo = 0, hi = 0;
                if (sh >= 0) {
                    if (sh < 64) {
                        lo = W << sh;
                        hi = sh ? (W >> (64 - sh)) : 0;
                    } else if (sh < 128) {
                        hi = W << (sh - 64);
                    }
                } else {
                    int r = -sh;
                    if (r < 64) lo = W >> r;
                }
                ulonglong2 pv; pv.x = lo; pv.y = hi;
                *(ulonglong2*)((char*)A_lds + m * 256 + (((f ^ (m & 7)) & 15) << 4)) = pv;
            }
        }
        __syncthreads();  // drains vmcnt (global_load_lds) + lgkm (ds_write)

        // MFMA: 4 k-steps of 32, 2x4 fragments per wave
#pragma unroll
        for (int kk = 0; kk < 4; ++kk) {
            bf16x8 af[2], bfr[4];
#pragma unroll
            for (int im = 0; im < 2; ++im) {
                int mrow = wm0 + im * 16 + (lane & 15);
                int slot = (kk * 4 + (lane >> 4)) ^ (mrow & 7);
                af[im] = *(const bf16x8*)((const char*)A_lds + mrow * 256 + slot * 16);
            }
#pragma unroll
            for (int in = 0; in < 4; ++in) {
                int orow = wn0 + in * 16 + (lane & 15);
                int slot = (kk * 4 + (lane >> 4)) ^ (orow & 7);
                bfr[in] = *(const bf16x8*)((const char*)B_lds + orow * 256 + slot * 16);
            }
#pragma unroll
            for (int im = 0; im < 2; ++im)
#pragma unroll
                for (int in = 0; in < 4; ++in)
                    acc[im][in] = __builtin_amdgcn_mfma_f32_16x16x32_bf16(
                        af[im], bfr[in], acc[im][in], 0, 0, 0);
        }
        __syncthreads();
    }

    // epilogue: acc -> bf16 via LDS (reuse A_lds), then vectorized global store.
#pragma unroll
    for (int im = 0; im < 2; ++im) {
        int rbase = wm0 + im * 16 + ((lane >> 4) << 2);
#pragma unroll
        for (int in = 0; in < 4; ++in) {
            int col = wn0 + in * 16 + (lane & 15);
#pragma unroll
            for (int r = 0; r < 4; ++r) {
                int row = rbase + r;
                int byte = row * 256 + ((col * 2) ^ ((row & 7) << 4));
                *(unsigned short*)((char*)A_lds + byte) = f2bf(acc[im][in][r]);
            }
        }
    }
    __syncthreads();
    for (int i = tid; i < BM * 16; i += 256) {
        int row = i >> 4, s = i & 15;
        int byte = row * 256 + ((s << 4) ^ ((row & 7) << 4));
        bf16x8 v = *(bf16x8*)((char*)A_lds + byte);
        int grow = gm0 + row;
        if (grow < N) *(bf16x8*)((char*)kanb + (size_t)grow * 256 + s * 16) = v;
    }
}

// ---------- CSR build ----------
__global__ void k_hist(const int* __restrict__ row, int* __restrict__ counts, int E) {
    int e = blockIdx.x * 256 + threadIdx.x;
    if (e < E) atomicAdd(&counts[row[e]], 1);
}

// 3-kernel coalesced scan
__global__ void k_scan1(const int* __restrict__ counts, int* __restrict__ bsum, int N) {
    int tid = threadIdx.x;
    int idx = blockIdx.x * 256 + tid;
    int v = (idx < N) ? counts[idx] : 0;
#pragma unroll
    for (int off = 32; off; off >>= 1) v += __shfl_xor(v, off, 64);
    __shared__ int ws[4];
    if ((tid & 63) == 0) ws[tid >> 6] = v;
    __syncthreads();
    if (tid == 0) bsum[blockIdx.x] = ws[0] + ws[1] + ws[2] + ws[3];
}

__global__ __launch_bounds__(1024) void k_scan2(const int* __restrict__ bsum,
                                                int* __restrict__ ebase,
                                                int* __restrict__ offsN, int nb) {
    __shared__ int ws[16];
    __shared__ int tot;
    int tid = threadIdx.x;
    int lane = tid & 63, w = tid >> 6;
    int v = (tid < nb) ? bsum[tid] : 0;
    int inc = v;
#pragma unroll
    for (int off = 1; off < 64; off <<= 1) {
        int t = __shfl_up(inc, off, 64);
        if (lane >= off) inc += t;
    }
    if (lane == 63) ws[w] = inc;
    __syncthreads();
    if (w == 0 && lane < 16) {
        int x = ws[lane];
#pragma unroll
        for (int off = 1; off < 16; off <<= 1) {
            int t = __shfl_up(x, off, 64);
            if (lane >= off) x += t;
        }
        ws[lane] = x;
        if (lane == 15) tot = x;
    }
    __syncthreads();
    int wb = w ? ws[w - 1] : 0;
    if (tid < nb) ebase[tid] = wb + inc - v;  // exclusive
    if (tid == 0) offsN[0] = tot;
}

__global__ void k_scan3(const int* __restrict__ counts, const int* __restrict__ ebase,
                        int* __restrict__ offsets, int N) {
    int tid = threadIdx.x;
    int idx = blockIdx.x * 256 + tid;
    int v = (idx < N) ? counts[idx] : 0;
    int lane = tid & 63, w = tid >> 6;
    int inc = v;
#pragma unroll
    for (int off = 1; off < 64; off <<= 1) {
        int t = __shfl_up(inc, off, 64);
        if (lane >= off) inc += t;
    }
    __shared__ int ws[4];
    if (lane == 63) ws[w] = inc;
    __syncthreads();
    int wb = 0;
    for (int i = 0; i < w; ++i) wb += ws[i];
    if (idx < N) offsets[idx] = ebase[blockIdx.x] + wb + inc - v;
}

__global__ void k_scatter(const int* __restrict__ row, const int* __restrict__ col,
                          const int* __restrict__ offsets, int* __restrict__ cursor,
                          int* __restrict__ cols_s, int E) {
    int e = blockIdx.x * 256 + threadIdx.x;
    if (e >= E) return;
    int r = row[e];
    int pos = offsets[r] + atomicAdd(&cursor[r], 1);
    cols_s[pos] = col[e];
}

// ---------- per-row softmax + bf16 gather-sum, with in-register canonical sort ----------
// The register bitonic sort (deg<=64) fixes the fp summation order deterministically
// regardless of the non-deterministic atomic scatter order — replaces k_sortrows.
__global__ __launch_bounds__(256) void k_aggr(const int* __restrict__ offsets,
                                              int* __restrict__ cols,
                                              const float* __restrict__ s_src,
                                              const float* __restrict__ s_dst,
                                              const unsigned short* __restrict__ kanb,
                                              float* __restrict__ out, int N) {
    int wid = (blockIdx.x * 256 + threadIdx.x) >> 6;
    int lane = threadIdx.x & 63;
    if (wid >= N) return;
    int start = offsets[wid], end = offsets[wid + 1];
    int deg = end - start;
    float acc0 = 0.f, acc1 = 0.f;
    if (deg > 0) {
        float ssrc = s_src[wid];
        if (deg <= 64) {
            int key = 0x7fffffff;
            if (lane < deg) key = cols[start + lane];
            // 64-wide bitonic sort, ascending
#pragma unroll
            for (int k = 2; k <= 64; k <<= 1) {
#pragma unroll
                for (int j = k >> 1; j > 0; j >>= 1) {
                    int other = __shfl_xor(key, j, 64);
                    bool asc = ((lane & k) == 0);
                    bool lowr = ((lane & j) == 0);
                    int mn = min(key, other), mx = max(key, other);
                    key = (asc == lowr) ? mn : mx;
                }
            }
            float e = -3.402823466e38f;
            if (lane < deg) {
                e = ssrc + s_dst[key];
                e = (e >= 0.f) ? e : 0.2f * e;
            }
            float m = e;
#pragma unroll
            for (int off = 32; off; off >>= 1) m = fmaxf(m, __shfl_xor(m, off, 64));
            float ex = (lane < deg) ? __expf(e - m) : 0.f;
            float s = ex;
#pragma unroll
            for (int off = 32; off; off >>= 1) s += __shfl_xor(s, off, 64);
            float att = ex / s;
            for (int q = 0; q < deg; ++q) {
                float w = __shfl(att, q, 64);
                int c = __shfl(key, q, 64);
                u32 p = ((const u32*)(kanb + (size_t)c * 128))[lane];
                float lo = __builtin_bit_cast(float, p << 16);
                float hi = __builtin_bit_cast(float, p & 0xffff0000u);
                acc0 = fmaf(w, lo, acc0);
                acc1 = fmaf(w, hi, acc1);
            }
        } else {
            // rare fallback: lane0 insertion-sorts the segment in place, then memory path
            if (lane == 0) {
                for (int i = start + 1; i < end; ++i) {
                    int v = cols[i];
                    int j = i - 1;
                    while (j >= start && cols[j] > v) { cols[j + 1] = cols[j]; --j; }
                    cols[j + 1] = v;
                }
            }
            __threadfence();
            float m = -3.402823466e38f;
            for (int j = start + lane; j < end; j += 64) {
                float e = ssrc + s_dst[cols[j]];
                e = (e >= 0.f) ? e : 0.2f * e;
                m = fmaxf(m, e);
            }
#pragma unroll
            for (int off = 32; off; off >>= 1) m = fmaxf(m, __shfl_xor(m, off, 64));
            float s = 0.f;
            for (int j = start + lane; j < end; j += 64) {
                float e = ssrc + s_dst[cols[j]];
                e = (e >= 0.f) ? e : 0.2f * e;
                s += __expf(e - m);
            }
#pragma unroll
            for (int off = 32; off; off >>= 1) s += __shfl_xor(s, off, 64);
            float inv = 1.0f / s;
            for (int t = start; t < end; t += 64) {
                int j = t + lane;
                float att = 0.f;
                int myc = 0;
                if (j < end) {
                    myc = cols[j];
                    float e = ssrc + s_dst[myc];
                    e = (e >= 0.f) ? e : 0.2f * e;
                    att = __expf(e - m) * inv;
                }
                int cnt = min(64, end - t);
                for (int q = 0; q < cnt; ++q) {
                    float w = __shfl(att, q, 64);
                    int c = __shfl(myc, q, 64);
                    u32 p = ((const u32*)(kanb + (size_t)c * 128))[lane];
                    float lo = __builtin_bit_cast(float, p << 16);
                    float hi = __builtin_bit_cast(float, p & 0xffff0000u);
                    acc0 = fmaf(w, lo, acc0);
                    acc1 = fmaf(w, hi, acc1);
                }
            }
        }
    }
    // lane covers cols 2*lane (acc0) and 2*lane+1 (acc1)
    float2 o2 = make_float2(acc0, acc1);
    *(float2*)(out + (size_t)wid * 128 + lane * 2) = o2;
}

extern "C" void kernel_launch(void* const* d_in, const int* in_sizes, int n_in,
                              void* d_out, int out_size, void* d_ws, size_t ws_size,
                              hipStream_t stream) {
    const float* h  = (const float*)d_in[0];
    const int*   ei = (const int*)d_in[1];
    const float* W  = (const float*)d_in[2];
    const float* a  = (const float*)d_in[3];
    const float* bw = (const float*)d_in[4];
    const float* sw = (const float*)d_in[5];
    float* out = (float*)d_out;
    const int N = in_sizes[0] / 128;
    const int E = in_sizes[1] / 2;
    const int nb = (N + 255) / 256;

    char* ws = (char*)d_ws;
    auto alloc = [&](size_t bytes) {
        char* p = ws;
        ws += (bytes + 255) & ~(size_t)255;
        return p;
    };
    unsigned short* Bsw = (unsigned short*)alloc((size_t)KTOT * 128 * 2);
    float* wa    = (float*)alloc(256 * 4);
    float* ssrc  = (float*)alloc((size_t)N * 4);
    float* sdst  = (float*)alloc((size_t)N * 4);
    unsigned short* kanb = (unsigned short*)alloc((size_t)N * 128 * 2);
    int* counts  = (int*)alloc((size_t)N * 4);
    int* cursor  = (int*)alloc((size_t)N * 4);
    int* offsets = (int*)alloc(((size_t)N + 1) * 4);
    int* colss   = (int*)alloc((size_t)E * 4);
    int* bsum    = (int*)alloc((size_t)nb * 4);
    int* ebase   = (int*)alloc((size_t)nb * 4);

    hipMemsetAsync(counts, 0, (size_t)N * 4, stream);
    hipMemsetAsync(cursor, 0, (size_t)N * 4, stream);

    k_prep<<<(NCHUNK * 128 * 128 + 255) / 256, 256, 0, stream>>>(bw, sw, Bsw);
    k_wa<<<1, 128, 0, stream>>>(W, a, wa);
    k_nodes<<<(N + BM - 1) / BM, 256, 0, stream>>>(h, Bsw, wa, kanb, ssrc, sdst, N);
    k_hist<<<(E + 255) / 256, 256, 0, stream>>>(ei, counts, E);
    k_scan1<<<nb, 256, 0, stream>>>(counts, bsum, N);
    k_scan2<<<1, 1024, 0, stream>>>(bsum, ebase, offsets + N, nb);
    k_scan3<<<nb, 256, 0, stream>>>(counts, ebase, offsets, N);
    k_scatter<<<(E + 255) / 256, 256, 0, stream>>>(ei, ei + E, offsets, cursor, colss, E);
    k_aggr<<<(N + 3) / 4, 256, 0, stream>>>(offsets, colss, ssrc, sdst, kanb, out, N);
}

// Round 7
// 193.328 us; speedup vs baseline: 2.8506x; 1.1987x over previous
//
#include <hip/hip_runtime.h>
#include <hip/hip_bf16.h>
#include <math.h>

#define NCHUNK 9
#define BM 64

typedef __attribute__((ext_vector_type(4))) float f32x4;
typedef __attribute__((ext_vector_type(8))) short bf16x8;
typedef unsigned int u32;
typedef unsigned long long u64;

__device__ __forceinline__ unsigned short f2bf(float f) {
    u32 u = __builtin_bit_cast(u32, f);
    u32 r = (u + 0x7FFFu + ((u >> 16) & 1u)) >> 16;
    return (unsigned short)r;
}

__device__ __forceinline__ float siluf(float x) {
    return x / (1.0f + __expf(-x));
}

// ---------- merged prep: blocks 0..575 build pre-swizzled Bsw; block 576 computes wa ----------
// Bsw element i = ((c*128 + o)*16 + s)*8 + j holds B[o][c*128 + (s^(o&7))*8 + j];
// linear global_load_lds of a chunk then lands the XOR-swizzled LDS image.
__global__ void k_prep(const float* __restrict__ bw, const float* __restrict__ sw,
                       const float* __restrict__ W, const float* __restrict__ a,
                       unsigned short* __restrict__ Bsw, float* __restrict__ wa) {
    if (blockIdx.x == (NCHUNK * 128 * 128) / 256) {
        int fi = threadIdx.x;
        if (fi < 128) {
            float s1 = 0.f, s2 = 0.f;
            for (int o = 0; o < 128; ++o) {
                float w = W[fi * 128 + o];
                s1 = fmaf(w, a[o], s1);
                s2 = fmaf(w, a[128 + o], s2);
            }
            wa[fi] = s1;
            wa[128 + fi] = s2;
        }
        return;
    }
    int i = blockIdx.x * 256 + threadIdx.x;
    int j = i & 7;
    int s = (i >> 3) & 15;
    int o = (i >> 7) & 127;
    int c = i >> 14;
    int k = c * 128 + (((s ^ (o & 7)) << 3) | j);
    float v = (k < 128) ? bw[o * 128 + k] : sw[o * 1024 + (k - 128)];
    Bsw[i] = f2bf(v);
}

// ---------- main node kernel: bf16 MFMA GEMM + fused scores (at end) ----------
// LDS: A 16K + B 32K = 48 KB -> 3 blocks/CU. x prefetched one chunk ahead into VGPRs.
__global__ __launch_bounds__(256) void k_nodes(const float* __restrict__ h,
                                               const unsigned short* __restrict__ Bsw,
                                               const float* __restrict__ wa,
                                               unsigned short* __restrict__ kanb,
                                               float* __restrict__ s_src,
                                               float* __restrict__ s_dst, int N) {
    __shared__ unsigned short A_lds[BM * 128];  // 16 KB, XOR-swizzled (reused for C out)
    __shared__ unsigned short B_lds[128 * 128]; // 32 KB, XOR-swizzled (pre-swz global)
    const int tid = threadIdx.x;
    const int wid = tid >> 6, lane = tid & 63;
    const int gm0 = blockIdx.x * BM;

    // gen mapping: thread owns (row gm, slot-quad gq) — 4 slots of 8 features
    const int gm = tid >> 2, gq = tid & 3;
    const float* ghr = h + (size_t)min(gm0 + gm, N - 1) * 128;

    const int wm0 = (wid >> 1) * 32;  // wave row offset within tile
    const int wn0 = (wid & 1) * 64;   // wave col offset
    f32x4 acc[2][4];
#pragma unroll
    for (int im = 0; im < 2; ++im)
#pragma unroll
        for (int in = 0; in < 4; ++in) acc[im][in] = {0.f, 0.f, 0.f, 0.f};

    f32x4 pf = {0.f, 0.f, 0.f, 0.f};  // spline x for current chunk (valid for chunk>=1)
    for (int chunk = 0; chunk < NCHUNK; ++chunk) {
        // async-stage B chunk (32 KB): each wave copies its 8 KB segment
        {
            const char* gsrc = (const char*)Bsw + (size_t)chunk * 32768 + wid * 8192 + lane * 16;
            char* ldst = (char*)B_lds + wid * 8192;
#pragma unroll
            for (int i = 0; i < 8; ++i) {
                __builtin_amdgcn_global_load_lds(
                    (const __attribute__((address_space(1))) u32*)(gsrc + i * 1024),
                    (__attribute__((address_space(3))) u32*)(ldst + i * 1024), 16, 0, 0);
            }
        }
        // prefetch x for chunk+1: its fb = ((chunk+1)-1)*16 = chunk*16
        f32x4 pfn = pf;
        if (chunk <= 7) pfn = *(const f32x4*)(ghr + chunk * 16 + gq * 4);

        if (chunk == 0) {
            // silu slots: thread covers features gq*32 .. gq*32+31
            f32x4 xv[8];
#pragma unroll
            for (int v = 0; v < 8; ++v) xv[v] = *(const f32x4*)(ghr + gq * 32 + v * 4);
#pragma unroll
            for (int sl = 0; sl < 4; ++sl) {
                int s = gq * 4 + sl;
                unsigned short pk[8];
#pragma unroll
                for (int j = 0; j < 4; ++j) {
                    pk[j] = f2bf(siluf(xv[2 * sl][j]));
                    pk[4 + j] = f2bf(siluf(xv[2 * sl + 1][j]));
                }
                *(bf16x8*)((char*)A_lds + gm * 256 + (((s ^ (gm & 7)) & 15) << 4)) =
                    *(bf16x8*)pk;
            }
        } else {
            // closed-form cardinal cubic B-spline on the uniform grid (see R4 notes)
#pragma unroll
            for (int j = 0; j < 4; ++j) {
                float x = pf[j];
                float t = (x + 2.2f) * 2.5f;
                float fl = floorf(t);
                int i0 = (int)fl;
                float u = t - fl;
                float um = 1.0f - u;
                float u2 = u * u, u3 = u2 * u;
                const float c6 = 1.0f / 6.0f;
                float w0 = um * um * um * c6;
                float w1 = (3.f * u3 - 6.f * u2 + 4.f) * c6;
                float w2 = (-3.f * u3 + 3.f * u2 + 3.f * u + 1.f) * c6;
                float w3 = u3 * c6;
                u64 Wp = (u64)f2bf(w0) | ((u64)f2bf(w1) << 16) |
                         ((u64)f2bf(w2) << 32) | ((u64)f2bf(w3) << 48);
                int sh = (i0 - 3) * 16;  // slot j0 = i0-3, 16 bits per bf16 slot
                u64 lo = 0, hi = 0;
                if (sh >= 0) {
                    if (sh < 64) {
                        lo = Wp << sh;
                        hi = sh ? (Wp >> (64 - sh)) : 0;
                    } else if (sh < 128) {
                        hi = Wp << (sh - 64);
                    }
                } else {
                    int r = -sh;
                    if (r < 64) lo = Wp >> r;
                }
                int s = gq * 4 + j;
                ulonglong2 pv; pv.x = lo; pv.y = hi;
                *(ulonglong2*)((char*)A_lds + gm * 256 + (((s ^ (gm & 7)) & 15) << 4)) = pv;
            }
        }
        __syncthreads();  // drains vmcnt (global_load_lds) + lgkm (ds_write)

        // MFMA: 4 k-steps of 32, 2x4 fragments per wave
#pragma unroll
        for (int kk = 0; kk < 4; ++kk) {
            bf16x8 af[2], bfr[4];
#pragma unroll
            for (int im = 0; im < 2; ++im) {
                int mrow = wm0 + im * 16 + (lane & 15);
                int slot = (kk * 4 + (lane >> 4)) ^ (mrow & 7);
                af[im] = *(const bf16x8*)((const char*)A_lds + mrow * 256 + slot * 16);
            }
#pragma unroll
            for (int in = 0; in < 4; ++in) {
                int orow = wn0 + in * 16 + (lane & 15);
                int slot = (kk * 4 + (lane >> 4)) ^ (orow & 7);
                bfr[in] = *(const bf16x8*)((const char*)B_lds + orow * 256 + slot * 16);
            }
#pragma unroll
            for (int im = 0; im < 2; ++im)
#pragma unroll
                for (int in = 0; in < 4; ++in)
                    acc[im][in] = __builtin_amdgcn_mfma_f32_16x16x32_bf16(
                        af[im], bfr[in], acc[im][in], 0, 0, 0);
        }
        __syncthreads();
        pf = pfn;
    }

    // batched score loads (issued early; latency hides under the epilogue)
    float wa0 = wa[lane], wa1 = wa[64 + lane];
    float wa2 = wa[128 + lane], wa3 = wa[192 + lane];
    float sx0[16], sx1[16];
    const int r0 = gm0 + wid * 16;
#pragma unroll
    for (int rr = 0; rr < 16; ++rr) {
        const float* hr = h + (size_t)min(r0 + rr, N - 1) * 128;
        sx0[rr] = hr[lane];
        sx1[rr] = hr[64 + lane];
    }

    // epilogue: acc -> bf16 via LDS (reuse A_lds), then vectorized global store.
#pragma unroll
    for (int im = 0; im < 2; ++im) {
        int rbase = wm0 + im * 16 + ((lane >> 4) << 2);
#pragma unroll
        for (int in = 0; in < 4; ++in) {
            int col = wn0 + in * 16 + (lane & 15);
#pragma unroll
            for (int r = 0; r < 4; ++r) {
                int row = rbase + r;
                int byte = row * 256 + ((col * 2) ^ ((row & 7) << 4));
                *(unsigned short*)((char*)A_lds + byte) = f2bf(acc[im][in][r]);
            }
        }
    }
    __syncthreads();
    for (int i = tid; i < BM * 16; i += 256) {
        int row = i >> 4, s = i & 15;
        int byte = row * 256 + ((s << 4) ^ ((row & 7) << 4));
        bf16x8 v = *(bf16x8*)((char*)A_lds + byte);
        int grow = gm0 + row;
        if (grow < N) *(bf16x8*)((char*)kanb + (size_t)grow * 256 + s * 16) = v;
    }

    // score reductions (16 independent shuffle-reduce chains)
#pragma unroll
    for (int rr = 0; rr < 16; ++rr) {
        float s1 = fmaf(sx0[rr], wa0, sx1[rr] * wa1);
        float s2 = fmaf(sx0[rr], wa2, sx1[rr] * wa3);
#pragma unroll
        for (int off = 32; off; off >>= 1) {
            s1 += __shfl_xor(s1, off, 64);
            s2 += __shfl_xor(s2, off, 64);
        }
        int grow = r0 + rr;
        if (lane == 0 && grow < N) {
            s_src[grow] = s1;
            s_dst[grow] = s2;
        }
    }
}

// ---------- CSR build ----------
__global__ void k_hist(const int* __restrict__ row, int* __restrict__ counts, int E) {
    int e = blockIdx.x * 256 + threadIdx.x;
    if (e < E) atomicAdd(&counts[row[e]], 1);
}

__global__ void k_scan1(const int* __restrict__ counts, int* __restrict__ bsum, int N) {
    int tid = threadIdx.x;
    int idx = blockIdx.x * 256 + tid;
    int v = (idx < N) ? counts[idx] : 0;
#pragma unroll
    for (int off = 32; off; off >>= 1) v += __shfl_xor(v, off, 64);
    __shared__ int ws[4];
    if ((tid & 63) == 0) ws[tid >> 6] = v;
    __syncthreads();
    if (tid == 0) bsum[blockIdx.x] = ws[0] + ws[1] + ws[2] + ws[3];
}

__global__ __launch_bounds__(1024) void k_scan2(const int* __restrict__ bsum,
                                                int* __restrict__ ebase,
                                                int* __restrict__ offsN, int nb) {
    __shared__ int ws[16];
    __shared__ int tot;
    int tid = threadIdx.x;
    int lane = tid & 63, w = tid >> 6;
    int v = (tid < nb) ? bsum[tid] : 0;
    int inc = v;
#pragma unroll
    for (int off = 1; off < 64; off <<= 1) {
        int t = __shfl_up(inc, off, 64);
        if (lane >= off) inc += t;
    }
    if (lane == 63) ws[w] = inc;
    __syncthreads();
    if (w == 0 && lane < 16) {
        int x = ws[lane];
#pragma unroll
        for (int off = 1; off < 16; off <<= 1) {
            int t = __shfl_up(x, off, 64);
            if (lane >= off) x += t;
        }
        ws[lane] = x;
        if (lane == 15) tot = x;
    }
    __syncthreads();
    int wb = w ? ws[w - 1] : 0;
    if (tid < nb) ebase[tid] = wb + inc - v;  // exclusive
    if (tid == 0) offsN[0] = tot;
}

__global__ void k_scan3(const int* __restrict__ counts, const int* __restrict__ ebase,
                        int* __restrict__ offsets, int N) {
    int tid = threadIdx.x;
    int idx = blockIdx.x * 256 + tid;
    int v = (idx < N) ? counts[idx] : 0;
    int lane = tid & 63, w = tid >> 6;
    int inc = v;
#pragma unroll
    for (int off = 1; off < 64; off <<= 1) {
        int t = __shfl_up(inc, off, 64);
        if (lane >= off) inc += t;
    }
    __shared__ int ws[4];
    if (lane == 63) ws[w] = inc;
    __syncthreads();
    int wb = 0;
    for (int i = 0; i < w; ++i) wb += ws[i];
    if (idx < N) offsets[idx] = ebase[blockIdx.x] + wb + inc - v;
}

__global__ void k_scatter(const int* __restrict__ row, const int* __restrict__ col,
                          const int* __restrict__ offsets, int* __restrict__ cursor,
                          int* __restrict__ cols_s, int E) {
    int e = blockIdx.x * 256 + threadIdx.x;
    if (e >= E) return;
    int r = row[e];
    int pos = offsets[r] + atomicAdd(&cursor[r], 1);
    cols_s[pos] = col[e];
}

// ---------- per-row softmax + bf16 gather-sum, in-register canonical sort ----------
__global__ __launch_bounds__(256) void k_aggr(const int* __restrict__ offsets,
                                              int* __restrict__ cols,
                                              const float* __restrict__ s_src,
                                              const float* __restrict__ s_dst,
                                              const unsigned short* __restrict__ kanb,
                                              float* __restrict__ out, int N) {
    int wid = (blockIdx.x * 256 + threadIdx.x) >> 6;
    int lane = threadIdx.x & 63;
    if (wid >= N) return;
    int start = offsets[wid], end = offsets[wid + 1];
    int deg = end - start;
    float acc0 = 0.f, acc1 = 0.f;
    if (deg > 0) {
        float ssrc = s_src[wid];
        if (deg <= 64) {
            int key = 0x7fffffff;
            if (lane < deg) key = cols[start + lane];
            // 64-wide bitonic sort, ascending (canonical order -> determinism)
#pragma unroll
            for (int k = 2; k <= 64; k <<= 1) {
#pragma unroll
                for (int j = k >> 1; j > 0; j >>= 1) {
                    int other = __shfl_xor(key, j, 64);
                    bool asc = ((lane & k) == 0);
                    bool lowr = ((lane & j) == 0);
                    int mn = min(key, other), mx = max(key, other);
                    key = (asc == lowr) ? mn : mx;
                }
            }
            float e = -3.402823466e38f;
            if (lane < deg) {
                e = ssrc + s_dst[key];
                e = (e >= 0.f) ? e : 0.2f * e;
            }
            float m = e;
#pragma unroll
            for (int off = 32; off; off >>= 1) m = fmaxf(m, __shfl_xor(m, off, 64));
            float ex = (lane < deg) ? __expf(e - m) : 0.f;
            float s = ex;
#pragma unroll
            for (int off = 32; off; off >>= 1) s += __shfl_xor(s, off, 64);
            float att = ex / s;
            // 4-way unrolled gather: 4 row-loads in flight per step
            for (int q0 = 0; q0 < deg; q0 += 4) {
                float w[4];
                u32 p[4];
#pragma unroll
                for (int t = 0; t < 4; ++t) {
                    int q = q0 + t;
                    int c = __shfl(key, q < deg ? q : 0, 64);
                    float wt = __shfl(att, q < 64 ? q : 0, 64);
                    w[t] = (q < deg) ? wt : 0.f;
                    p[t] = ((const u32*)(kanb + (size_t)c * 128))[lane];
                }
#pragma unroll
                for (int t = 0; t < 4; ++t) {
                    float lo = __builtin_bit_cast(float, p[t] << 16);
                    float hi = __builtin_bit_cast(float, p[t] & 0xffff0000u);
                    acc0 = fmaf(w[t], lo, acc0);
                    acc1 = fmaf(w[t], hi, acc1);
                }
            }
        } else {
            // rare fallback: lane0 insertion-sorts the segment in place, then memory path
            if (lane == 0) {
                for (int i = start + 1; i < end; ++i) {
                    int v = cols[i];
                    int j = i - 1;
                    while (j >= start && cols[j] > v) { cols[j + 1] = cols[j]; --j; }
                    cols[j + 1] = v;
                }
            }
            __threadfence();
            float m = -3.402823466e38f;
            for (int j = start + lane; j < end; j += 64) {
                float e = ssrc + s_dst[cols[j]];
                e = (e >= 0.f) ? e : 0.2f * e;
                m = fmaxf(m, e);
            }
#pragma unroll
            for (int off = 32; off; off >>= 1) m = fmaxf(m, __shfl_xor(m, off, 64));
            float s = 0.f;
            for (int j = start + lane; j < end; j += 64) {
                float e = ssrc + s_dst[cols[j]];
                e = (e >= 0.f) ? e : 0.2f * e;
                s += __expf(e - m);
            }
#pragma unroll
            for (int off = 32; off; off >>= 1) s += __shfl_xor(s, off, 64);
            float inv = 1.0f / s;
            for (int t = start; t < end; t += 64) {
                int j = t + lane;
                float att = 0.f;
                int myc = 0;
                if (j < end) {
                    myc = cols[j];
                    float e = ssrc + s_dst[myc];
                    e = (e >= 0.f) ? e : 0.2f * e;
                    att = __expf(e - m) * inv;
                }
                int cnt = min(64, end - t);
                for (int q = 0; q < cnt; ++q) {
                    float w = __shfl(att, q, 64);
                    int c = __shfl(myc, q, 64);
                    u32 p = ((const u32*)(kanb + (size_t)c * 128))[lane];
                    float lo = __builtin_bit_cast(float, p << 16);
                    float hi = __builtin_bit_cast(float, p & 0xffff0000u);
                    acc0 = fmaf(w, lo, acc0);
                    acc1 = fmaf(w, hi, acc1);
                }
            }
        }
    }
    float2 o2 = make_float2(acc0, acc1);
    *(float2*)(out + (size_t)wid * 128 + lane * 2) = o2;
}

extern "C" void kernel_launch(void* const* d_in, const int* in_sizes, int n_in,
                              void* d_out, int out_size, void* d_ws, size_t ws_size,
                              hipStream_t stream) {
    const float* h  = (const float*)d_in[0];
    const int*   ei = (const int*)d_in[1];
    const float* W  = (const float*)d_in[2];
    const float* a  = (const float*)d_in[3];
    const float* bw = (const float*)d_in[4];
    const float* sw = (const float*)d_in[5];
    float* out = (float*)d_out;
    const int N = in_sizes[0] / 128;
    const int E = in_sizes[1] / 2;
    const int nb = (N + 255) / 256;

    char* ws = (char*)d_ws;
    auto alloc = [&](size_t bytes) {
        char* p = ws;
        ws += (bytes + 255) & ~(size_t)255;
        return p;
    };
    unsigned short* Bsw = (unsigned short*)alloc((size_t)NCHUNK * 128 * 128 * 2);
    float* wa    = (float*)alloc(256 * 4);
    float* ssrc  = (float*)alloc((size_t)N * 4);
    float* sdst  = (float*)alloc((size_t)N * 4);
    unsigned short* kanb = (unsigned short*)alloc((size_t)N * 128 * 2);
    int* counts  = (int*)alloc((size_t)N * 4);
    int* cursor  = (int*)alloc((size_t)N * 4);
    int* offsets = (int*)alloc(((size_t)N + 1) * 4);
    int* colss   = (int*)alloc((size_t)E * 4);
    int* bsum    = (int*)alloc((size_t)nb * 4);
    int* ebase   = (int*)alloc((size_t)nb * 4);

    hipMemsetAsync(counts, 0, (size_t)N * 4, stream);
    hipMemsetAsync(cursor, 0, (size_t)N * 4, stream);

    k_prep<<<(NCHUNK * 128 * 128) / 256 + 1, 256, 0, stream>>>(bw, sw, W, a, Bsw, wa);
    k_nodes<<<(N + BM - 1) / BM, 256, 0, stream>>>(h, Bsw, wa, kanb, ssrc, sdst, N);
    k_hist<<<(E + 255) / 256, 256, 0, stream>>>(ei, counts, E);
    k_scan1<<<nb, 256, 0, stream>>>(counts, bsum, N);
    k_scan2<<<1, 1024, 0, stream>>>(bsum, ebase, offsets + N, nb);
    k_scan3<<<nb, 256, 0, stream>>>(counts, ebase, offsets, N);
    k_scatter<<<(E + 255) / 256, 256, 0, stream>>>(ei, ei + E, offsets, cursor, colss, E);
    k_aggr<<<(N + 3) / 4, 256, 0, stream>>>(offsets, colss, ssrc, sdst, kanb, out, N);
}

// Round 8
// 148.287 us; speedup vs baseline: 3.7164x; 1.3037x over previous
//
#include <hip/hip_runtime.h>
#include <hip/hip_bf16.h>
#include <math.h>

#define NCHUNK 9
#define BM 128
#define NTHR 512
#define PREPB ((NCHUNK * 128 * 128) / 256)  // 576 Bsw blocks

typedef __attribute__((ext_vector_type(4))) float f32x4;
typedef __attribute__((ext_vector_type(8))) short bf16x8;
typedef unsigned int u32;
typedef unsigned long long u64;

__device__ __forceinline__ unsigned short f2bf(float f) {
    u32 u = __builtin_bit_cast(u32, f);
    u32 r = (u + 0x7FFFu + ((u >> 16) & 1u)) >> 16;
    return (unsigned short)r;
}

__device__ __forceinline__ float siluf(float x) {
    return x / (1.0f + __expf(-x));
}

// ---------- merged prep: Bsw build + wa + edge histogram (independent work fused) ----------
// Bsw element i = ((c*128 + o)*16 + s)*8 + j holds B[o][c*128 + (s^(o&7))*8 + j];
// linear global_load_lds of a chunk then lands the XOR-swizzled LDS image.
__global__ void k_prep(const float* __restrict__ bw, const float* __restrict__ sw,
                       const float* __restrict__ W, const float* __restrict__ a,
                       unsigned short* __restrict__ Bsw, float* __restrict__ wa,
                       const int* __restrict__ erow, int* __restrict__ counts, int E) {
    int bid = blockIdx.x;
    if (bid < PREPB) {
        int i = bid * 256 + threadIdx.x;
        int j = i & 7;
        int s = (i >> 3) & 15;
        int o = (i >> 7) & 127;
        int c = i >> 14;
        int k = c * 128 + (((s ^ (o & 7)) << 3) | j);
        float v = (k < 128) ? bw[o * 128 + k] : sw[o * 1024 + (k - 128)];
        Bsw[i] = f2bf(v);
        return;
    }
    if (bid == PREPB) {
        int fi = threadIdx.x;
        if (fi < 128) {
            float s1 = 0.f, s2 = 0.f;
            for (int o = 0; o < 128; ++o) {
                float w = W[fi * 128 + o];
                s1 = fmaf(w, a[o], s1);
                s2 = fmaf(w, a[128 + o], s2);
            }
            wa[fi] = s1;
            wa[128 + fi] = s2;
        }
        return;
    }
    // histogram tail blocks
    int e = (bid - PREPB - 1) * 256 + threadIdx.x;
    if (e < E) atomicAdd(&counts[erow[e]], 1);
}

// ---------- main node kernel: 128x128 bf16 MFMA GEMM + fused scores + fused scatter ----------
// LDS: A 32K + B 32K = 64 KB -> 2 blocks/CU (16 waves). Blocks >= nbn do the CSR scatter
// (independent memory-bound work overlapped with the compute-bound GEMM).
__global__ __launch_bounds__(NTHR) void k_nodes(const float* __restrict__ h,
                                                const unsigned short* __restrict__ Bsw,
                                                const float* __restrict__ wa,
                                                unsigned short* __restrict__ kanb,
                                                float* __restrict__ s_src,
                                                float* __restrict__ s_dst, int N, int nbn,
                                                const int* __restrict__ erow,
                                                const int* __restrict__ ecol,
                                                const int* __restrict__ offsets,
                                                int* __restrict__ cursor,
                                                int* __restrict__ colss, int E) {
    __shared__ unsigned short A_lds[BM * 128];  // 32 KB, XOR-swizzled (reused for C out)
    __shared__ unsigned short B_lds[128 * 128]; // 32 KB, XOR-swizzled (pre-swz global)
    const int tid = threadIdx.x;

    if (blockIdx.x >= nbn) {  // ---- scatter tail blocks ----
        int e = (blockIdx.x - nbn) * NTHR + tid;
        if (e < E) {
            int r = erow[e];
            int pos = offsets[r] + atomicAdd(&cursor[r], 1);
            colss[pos] = ecol[e];
        }
        return;
    }

    const int wid = tid >> 6, lane = tid & 63;
    const int gm0 = blockIdx.x * BM;

    // gen mapping: thread owns (row gm, slot-quad gq) — 4 slots of 8 features
    const int gm = tid >> 2, gq = tid & 3;
    const float* ghr = h + (size_t)min(gm0 + gm, N - 1) * 128;

    const int wm0 = (wid >> 1) * 32;  // wave row offset within tile (8 waves: 4m x 2n)
    const int wn0 = (wid & 1) * 64;   // wave col offset
    f32x4 acc[2][4];
#pragma unroll
    for (int im = 0; im < 2; ++im)
#pragma unroll
        for (int in = 0; in < 4; ++in) acc[im][in] = {0.f, 0.f, 0.f, 0.f};

    f32x4 pf = {0.f, 0.f, 0.f, 0.f};  // spline x for current chunk (valid for chunk>=1)
    for (int chunk = 0; chunk < NCHUNK; ++chunk) {
        // async-stage B chunk (32 KB): each of 8 waves copies its 4 KB segment
        {
            const char* gsrc = (const char*)Bsw + (size_t)chunk * 32768 + wid * 4096 + lane * 16;
            char* ldst = (char*)B_lds + wid * 4096;
#pragma unroll
            for (int i = 0; i < 4; ++i) {
                __builtin_amdgcn_global_load_lds(
                    (const __attribute__((address_space(1))) u32*)(gsrc + i * 1024),
                    (__attribute__((address_space(3))) u32*)(ldst + i * 1024), 16, 0, 0);
            }
        }
        // prefetch x for chunk+1: its fb = ((chunk+1)-1)*16 = chunk*16
        f32x4 pfn = pf;
        if (chunk <= 7) pfn = *(const f32x4*)(ghr + chunk * 16 + gq * 4);

        if (chunk == 0) {
            // silu slots: thread covers features gq*32 .. gq*32+31
            f32x4 xv[8];
#pragma unroll
            for (int v = 0; v < 8; ++v) xv[v] = *(const f32x4*)(ghr + gq * 32 + v * 4);
#pragma unroll
            for (int sl = 0; sl < 4; ++sl) {
                int s = gq * 4 + sl;
                unsigned short pk[8];
#pragma unroll
                for (int j = 0; j < 4; ++j) {
                    pk[j] = f2bf(siluf(xv[2 * sl][j]));
                    pk[4 + j] = f2bf(siluf(xv[2 * sl + 1][j]));
                }
                *(bf16x8*)((char*)A_lds + gm * 256 + (((s ^ (gm & 7)) & 15) << 4)) =
                    *(bf16x8*)pk;
            }
        } else {
            // closed-form cardinal cubic B-spline on the uniform grid (see R4 notes)
#pragma unroll
            for (int j = 0; j < 4; ++j) {
                float x = pf[j];
                float t = (x + 2.2f) * 2.5f;
                float fl = floorf(t);
                int i0 = (int)fl;
                float u = t - fl;
                float um = 1.0f - u;
                float u2 = u * u, u3 = u2 * u;
                const float c6 = 1.0f / 6.0f;
                float w0 = um * um * um * c6;
                float w1 = (3.f * u3 - 6.f * u2 + 4.f) * c6;
                float w2 = (-3.f * u3 + 3.f * u2 + 3.f * u + 1.f) * c6;
                float w3 = u3 * c6;
                u64 Wp = (u64)f2bf(w0) | ((u64)f2bf(w1) << 16) |
                         ((u64)f2bf(w2) << 32) | ((u64)f2bf(w3) << 48);
                int sh = (i0 - 3) * 16;  // slot j0 = i0-3, 16 bits per bf16 slot
                u64 lo = 0, hi = 0;
                if (sh >= 0) {
                    if (sh < 64) {
                        lo = Wp << sh;
                        hi = sh ? (Wp >> (64 - sh)) : 0;
                    } else if (sh < 128) {
                        hi = Wp << (sh - 64);
                    }
                } else {
                    int r = -sh;
                    if (r < 64) lo = Wp >> r;
                }
                int s = gq * 4 + j;
                ulonglong2 pv; pv.x = lo; pv.y = hi;
                *(ulonglong2*)((char*)A_lds + gm * 256 + (((s ^ (gm & 7)) & 15) << 4)) = pv;
            }
        }
        __syncthreads();  // drains vmcnt (global_load_lds) + lgkm (ds_write)

        // MFMA: 4 k-steps of 32, 2x4 fragments per wave
#pragma unroll
        for (int kk = 0; kk < 4; ++kk) {
            bf16x8 af[2], bfr[4];
#pragma unroll
            for (int im = 0; im < 2; ++im) {
                int mrow = wm0 + im * 16 + (lane & 15);
                int slot = (kk * 4 + (lane >> 4)) ^ (mrow & 7);
                af[im] = *(const bf16x8*)((const char*)A_lds + mrow * 256 + slot * 16);
            }
#pragma unroll
            for (int in = 0; in < 4; ++in) {
                int orow = wn0 + in * 16 + (lane & 15);
                int slot = (kk * 4 + (lane >> 4)) ^ (orow & 7);
                bfr[in] = *(const bf16x8*)((const char*)B_lds + orow * 256 + slot * 16);
            }
#pragma unroll
            for (int im = 0; im < 2; ++im)
#pragma unroll
                for (int in = 0; in < 4; ++in)
                    acc[im][in] = __builtin_amdgcn_mfma_f32_16x16x32_bf16(
                        af[im], bfr[in], acc[im][in], 0, 0, 0);
        }
        __syncthreads();
        pf = pfn;
    }

    // batched score loads (issued early; latency hides under the epilogue)
    float wa0 = wa[lane], wa1 = wa[64 + lane];
    float wa2 = wa[128 + lane], wa3 = wa[192 + lane];
    float sx0[16], sx1[16];
    const int r0 = gm0 + wid * 16;
#pragma unroll
    for (int rr = 0; rr < 16; ++rr) {
        const float* hr = h + (size_t)min(r0 + rr, N - 1) * 128;
        sx0[rr] = hr[lane];
        sx1[rr] = hr[64 + lane];
    }

    // epilogue: acc -> bf16 via LDS (reuse A_lds), then vectorized global store.
#pragma unroll
    for (int im = 0; im < 2; ++im) {
        int rbase = wm0 + im * 16 + ((lane >> 4) << 2);
#pragma unroll
        for (int in = 0; in < 4; ++in) {
            int col = wn0 + in * 16 + (lane & 15);
#pragma unroll
            for (int r = 0; r < 4; ++r) {
                int row = rbase + r;
                int byte = row * 256 + ((col * 2) ^ ((row & 7) << 4));
                *(unsigned short*)((char*)A_lds + byte) = f2bf(acc[im][in][r]);
            }
        }
    }
    __syncthreads();
    for (int i = tid; i < BM * 16; i += NTHR) {
        int row = i >> 4, s = i & 15;
        int byte = row * 256 + ((s << 4) ^ ((row & 7) << 4));
        bf16x8 v = *(bf16x8*)((char*)A_lds + byte);
        int grow = gm0 + row;
        if (grow < N) *(bf16x8*)((char*)kanb + (size_t)grow * 256 + s * 16) = v;
    }

    // score reductions (16 independent shuffle-reduce chains)
#pragma unroll
    for (int rr = 0; rr < 16; ++rr) {
        float s1 = fmaf(sx0[rr], wa0, sx1[rr] * wa1);
        float s2 = fmaf(sx0[rr], wa2, sx1[rr] * wa3);
#pragma unroll
        for (int off = 32; off; off >>= 1) {
            s1 += __shfl_xor(s1, off, 64);
            s2 += __shfl_xor(s2, off, 64);
        }
        int grow = r0 + rr;
        if (lane == 0 && grow < N) {
            s_src[grow] = s1;
            s_dst[grow] = s2;
        }
    }
}

// ---------- coalesced scan (3 tiny kernels) ----------
__global__ void k_scan1(const int* __restrict__ counts, int* __restrict__ bsum, int N) {
    int tid = threadIdx.x;
    int idx = blockIdx.x * 256 + tid;
    int v = (idx < N) ? counts[idx] : 0;
#pragma unroll
    for (int off = 32; off; off >>= 1) v += __shfl_xor(v, off, 64);
    __shared__ int ws[4];
    if ((tid & 63) == 0) ws[tid >> 6] = v;
    __syncthreads();
    if (tid == 0) bsum[blockIdx.x] = ws[0] + ws[1] + ws[2] + ws[3];
}

__global__ __launch_bounds__(1024) void k_scan2(const int* __restrict__ bsum,
                                                int* __restrict__ ebase,
                                                int* __restrict__ offsN, int nb) {
    __shared__ int ws[16];
    __shared__ int tot;
    int tid = threadIdx.x;
    int lane = tid & 63, w = tid >> 6;
    int v = (tid < nb) ? bsum[tid] : 0;
    int inc = v;
#pragma unroll
    for (int off = 1; off < 64; off <<= 1) {
        int t = __shfl_up(inc, off, 64);
        if (lane >= off) inc += t;
    }
    if (lane == 63) ws[w] = inc;
    __syncthreads();
    if (w == 0 && lane < 16) {
        int x = ws[lane];
#pragma unroll
        for (int off = 1; off < 16; off <<= 1) {
            int t = __shfl_up(x, off, 64);
            if (lane >= off) x += t;
        }
        ws[lane] = x;
        if (lane == 15) tot = x;
    }
    __syncthreads();
    int wb = w ? ws[w - 1] : 0;
    if (tid < nb) ebase[tid] = wb + inc - v;  // exclusive
    if (tid == 0) offsN[0] = tot;
}

__global__ void k_scan3(const int* __restrict__ counts, const int* __restrict__ ebase,
                        int* __restrict__ offsets, int N) {
    int tid = threadIdx.x;
    int idx = blockIdx.x * 256 + tid;
    int v = (idx < N) ? counts[idx] : 0;
    int lane = tid & 63, w = tid >> 6;
    int inc = v;
#pragma unroll
    for (int off = 1; off < 64; off <<= 1) {
        int t = __shfl_up(inc, off, 64);
        if (lane >= off) inc += t;
    }
    __shared__ int ws[4];
    if (lane == 63) ws[w] = inc;
    __syncthreads();
    int wb = 0;
    for (int i = 0; i < w; ++i) wb += ws[i];
    if (idx < N) offsets[idx] = ebase[blockIdx.x] + wb + inc - v;
}

// ---------- per-row softmax + bf16 gather-sum, in-register canonical sort ----------
__global__ __launch_bounds__(256) void k_aggr(const int* __restrict__ offsets,
                                              int* __restrict__ cols,
                                              const float* __restrict__ s_src,
                                              const float* __restrict__ s_dst,
                                              const unsigned short* __restrict__ kanb,
                                              float* __restrict__ out, int N) {
    int wid = (blockIdx.x * 256 + threadIdx.x) >> 6;
    int lane = threadIdx.x & 63;
    if (wid >= N) return;
    int start = offsets[wid], end = offsets[wid + 1];
    int deg = end - start;
    float acc0 = 0.f, acc1 = 0.f;
    if (deg > 0) {
        float ssrc = s_src[wid];
        if (deg <= 64) {
            int key = 0x7fffffff;
            if (lane < deg) key = cols[start + lane];
            // 64-wide bitonic sort, ascending (canonical order -> determinism)
#pragma unroll
            for (int k = 2; k <= 64; k <<= 1) {
#pragma unroll
                for (int j = k >> 1; j > 0; j >>= 1) {
                    int other = __shfl_xor(key, j, 64);
                    bool asc = ((lane & k) == 0);
                    bool lowr = ((lane & j) == 0);
                    int mn = min(key, other), mx = max(key, other);
                    key = (asc == lowr) ? mn : mx;
                }
            }
            float e = -3.402823466e38f;
            if (lane < deg) {
                e = ssrc + s_dst[key];
                e = (e >= 0.f) ? e : 0.2f * e;
            }
            float m = e;
#pragma unroll
            for (int off = 32; off; off >>= 1) m = fmaxf(m, __shfl_xor(m, off, 64));
            float ex = (lane < deg) ? __expf(e - m) : 0.f;
            float s = ex;
#pragma unroll
            for (int off = 32; off; off >>= 1) s += __shfl_xor(s, off, 64);
            float att = ex / s;
            // 4-way unrolled gather: 4 row-loads in flight per step
            for (int q0 = 0; q0 < deg; q0 += 4) {
                float w[4];
                u32 p[4];
#pragma unroll
                for (int t = 0; t < 4; ++t) {
                    int q = q0 + t;
                    int c = __shfl(key, q < deg ? q : 0, 64);
                    float wt = __shfl(att, q < 64 ? q : 0, 64);
                    w[t] = (q < deg) ? wt : 0.f;
                    p[t] = ((const u32*)(kanb + (size_t)c * 128))[lane];
                }
#pragma unroll
                for (int t = 0; t < 4; ++t) {
                    float lo = __builtin_bit_cast(float, p[t] << 16);
                    float hi = __builtin_bit_cast(float, p[t] & 0xffff0000u);
                    acc0 = fmaf(w[t], lo, acc0);
                    acc1 = fmaf(w[t], hi, acc1);
                }
            }
        } else {
            // rare fallback: lane0 insertion-sorts the segment in place, then memory path
            if (lane == 0) {
                for (int i = start + 1; i < end; ++i) {
                    int v = cols[i];
                    int j = i - 1;
                    while (j >= start && cols[j] > v) { cols[j + 1] = cols[j]; --j; }
                    cols[j + 1] = v;
                }
            }
            __threadfence();
            float m = -3.402823466e38f;
            for (int j = start + lane; j < end; j += 64) {
                float e = ssrc + s_dst[cols[j]];
                e = (e >= 0.f) ? e : 0.2f * e;
                m = fmaxf(m, e);
            }
#pragma unroll
            for (int off = 32; off; off >>= 1) m = fmaxf(m, __shfl_xor(m, off, 64));
            float s = 0.f;
            for (int j = start + lane; j < end; j += 64) {
                float e = ssrc + s_dst[cols[j]];
                e = (e >= 0.f) ? e : 0.2f * e;
                s += __expf(e - m);
            }
#pragma unroll
            for (int off = 32; off; off >>= 1) s += __shfl_xor(s, off, 64);
            float inv = 1.0f / s;
            for (int t = start; t < end; t += 64) {
                int j = t + lane;
                float att = 0.f;
                int myc = 0;
                if (j < end) {
                    myc = cols[j];
                    float e = ssrc + s_dst[myc];
                    e = (e >= 0.f) ? e : 0.2f * e;
                    att = __expf(e - m) * inv;
                }
                int cnt = min(64, end - t);
                for (int q = 0; q < cnt; ++q) {
                    float w = __shfl(att, q, 64);
                    int c = __shfl(myc, q, 64);
                    u32 p = ((const u32*)(kanb + (size_t)c * 128))[lane];
                    float lo = __builtin_bit_cast(float, p << 16);
                    float hi = __builtin_bit_cast(float, p & 0xffff0000u);
                    acc0 = fmaf(w, lo, acc0);
                    acc1 = fmaf(w, hi, acc1);
                }
            }
        }
    }
    float2 o2 = make_float2(acc0, acc1);
    *(float2*)(out + (size_t)wid * 128 + lane * 2) = o2;
}

extern "C" void kernel_launch(void* const* d_in, const int* in_sizes, int n_in,
                              void* d_out, int out_size, void* d_ws, size_t ws_size,
                              hipStream_t stream) {
    const float* h  = (const float*)d_in[0];
    const int*   ei = (const int*)d_in[1];
    const float* W  = (const float*)d_in[2];
    const float* a  = (const float*)d_in[3];
    const float* bw = (const float*)d_in[4];
    const float* sw = (const float*)d_in[5];
    float* out = (float*)d_out;
    const int N = in_sizes[0] / 128;
    const int E = in_sizes[1] / 2;
    const int nb = (N + 255) / 256;
    const int nbn = (N + BM - 1) / BM;              // node tiles
    const int nbs = (E + NTHR - 1) / NTHR;          // scatter tail blocks
    const int nbh = (E + 255) / 256;                // hist tail blocks

    char* ws = (char*)d_ws;
    auto alloc = [&](size_t bytes) {
        char* p = ws;
        ws += (bytes + 255) & ~(size_t)255;
        return p;
    };
    unsigned short* Bsw = (unsigned short*)alloc((size_t)NCHUNK * 128 * 128 * 2);
    float* wa    = (float*)alloc(256 * 4);
    float* ssrc  = (float*)alloc((size_t)N * 4);
    float* sdst  = (float*)alloc((size_t)N * 4);
    unsigned short* kanb = (unsigned short*)alloc((size_t)N * 128 * 2);
    int* counts  = (int*)alloc((size_t)N * 4);
    int* cursor  = (int*)alloc((size_t)N * 4);
    int* offsets = (int*)alloc(((size_t)N + 1) * 4);
    int* colss   = (int*)alloc((size_t)E * 4);
    int* bsum    = (int*)alloc((size_t)nb * 4);
    int* ebase   = (int*)alloc((size_t)nb * 4);

    hipMemsetAsync(counts, 0, (size_t)N * 4, stream);
    hipMemsetAsync(cursor, 0, (size_t)N * 4, stream);

    k_prep<<<PREPB + 1 + nbh, 256, 0, stream>>>(bw, sw, W, a, Bsw, wa, ei, counts, E);
    k_scan1<<<nb, 256, 0, stream>>>(counts, bsum, N);
    k_scan2<<<1, 1024, 0, stream>>>(bsum, ebase, offsets + N, nb);
    k_scan3<<<nb, 256, 0, stream>>>(counts, ebase, offsets, N);
    k_nodes<<<nbn + nbs, NTHR, 0, stream>>>(h, Bsw, wa, kanb, ssrc, sdst, N, nbn,
                                            ei, ei + E, offsets, cursor, colss, E);
    k_aggr<<<(N + 3) / 4, 256, 0, stream>>>(offsets, colss, ssrc, sdst, kanb, out, N);
}

// Round 9
// 147.886 us; speedup vs baseline: 3.7265x; 1.0027x over previous
//
#include <hip/hip_runtime.h>
#include <hip/hip_bf16.h>
#include <math.h>

#define NCHUNK 9
#define BM 128
#define NTHR 512
#define PREPB ((NCHUNK * 128 * 128) / 256)  // 576 Bsw blocks

typedef __attribute__((ext_vector_type(4))) float f32x4;
typedef __attribute__((ext_vector_type(8))) short bf16x8;
typedef unsigned int u32;
typedef unsigned long long u64;

__device__ __forceinline__ unsigned short f2bf(float f) {
    u32 u = __builtin_bit_cast(u32, f);
    u32 r = (u + 0x7FFFu + ((u >> 16) & 1u)) >> 16;
    return (unsigned short)r;
}

__device__ __forceinline__ float siluf(float x) {
    return x / (1.0f + __expf(-x));
}

// ---------- merged prep: Bsw build + wa + edge histogram (independent work fused) ----------
// Bsw element i = ((c*128 + o)*16 + s)*8 + j holds B[o][c*128 + (s^(o&7))*8 + j];
// linear global_load_lds of a chunk then lands the XOR-swizzled LDS image.
__global__ void k_prep(const float* __restrict__ bw, const float* __restrict__ sw,
                       const float* __restrict__ W, const float* __restrict__ a,
                       unsigned short* __restrict__ Bsw, float* __restrict__ wa,
                       const int* __restrict__ erow, int* __restrict__ counts, int E) {
    int bid = blockIdx.x;
    if (bid < PREPB) {
        int i = bid * 256 + threadIdx.x;
        int j = i & 7;
        int s = (i >> 3) & 15;
        int o = (i >> 7) & 127;
        int c = i >> 14;
        int k = c * 128 + (((s ^ (o & 7)) << 3) | j);
        float v = (k < 128) ? bw[o * 128 + k] : sw[o * 1024 + (k - 128)];
        Bsw[i] = f2bf(v);
        return;
    }
    if (bid == PREPB) {
        int fi = threadIdx.x;
        if (fi < 128) {
            float s1 = 0.f, s2 = 0.f;
            for (int o = 0; o < 128; ++o) {
                float w = W[fi * 128 + o];
                s1 = fmaf(w, a[o], s1);
                s2 = fmaf(w, a[128 + o], s2);
            }
            wa[fi] = s1;
            wa[128 + fi] = s2;
        }
        return;
    }
    // histogram tail blocks
    int e = (bid - PREPB - 1) * 256 + threadIdx.x;
    if (e < E) atomicAdd(&counts[erow[e]], 1);
}

// ---------- main node kernel: 128x128 bf16 MFMA GEMM + fused scores + fused scatter ----------
// LDS: A 32K + B 32K = 64 KB -> 2 blocks/CU. Blocks >= nbn do the CSR scatter
// (independent memory-bound work overlapped with the compute-bound GEMM).
__global__ __launch_bounds__(NTHR) void k_nodes(const float* __restrict__ h,
                                                const unsigned short* __restrict__ Bsw,
                                                const float* __restrict__ wa,
                                                unsigned short* __restrict__ kanb,
                                                float* __restrict__ s_src,
                                                float* __restrict__ s_dst, int N, int nbn,
                                                const int* __restrict__ erow,
                                                const int* __restrict__ ecol,
                                                const int* __restrict__ offsets,
                                                int* __restrict__ cursor,
                                                int* __restrict__ colss, int E) {
    __shared__ unsigned short A_lds[BM * 128];  // 32 KB, XOR-swizzled (reused for C out)
    __shared__ unsigned short B_lds[128 * 128]; // 32 KB, XOR-swizzled (pre-swz global)
    const int tid = threadIdx.x;

    if (blockIdx.x >= nbn) {  // ---- scatter tail blocks ----
        int e = (blockIdx.x - nbn) * NTHR + tid;
        if (e < E) {
            int r = erow[e];
            int pos = offsets[r] + atomicAdd(&cursor[r], 1);
            colss[pos] = ecol[e];
        }
        return;
    }

    const int wid = tid >> 6, lane = tid & 63;
    const int gm0 = blockIdx.x * BM;

    // gen mapping: thread owns (row gm, slot-quad gq) — 4 slots of 8 features
    const int gm = tid >> 2, gq = tid & 3;
    const float* ghr = h + (size_t)min(gm0 + gm, N - 1) * 128;

    const int wm0 = (wid >> 1) * 32;  // wave row offset within tile (8 waves: 4m x 2n)
    const int wn0 = (wid & 1) * 64;   // wave col offset
    f32x4 acc[2][4];
#pragma unroll
    for (int im = 0; im < 2; ++im)
#pragma unroll
        for (int in = 0; in < 4; ++in) acc[im][in] = {0.f, 0.f, 0.f, 0.f};

    f32x4 pf = {0.f, 0.f, 0.f, 0.f};  // spline x for current chunk (valid for chunk>=1)
    for (int chunk = 0; chunk < NCHUNK; ++chunk) {
        // async-stage B chunk (32 KB): each of 8 waves copies its 4 KB segment
        {
            const char* gsrc = (const char*)Bsw + (size_t)chunk * 32768 + wid * 4096 + lane * 16;
            char* ldst = (char*)B_lds + wid * 4096;
#pragma unroll
            for (int i = 0; i < 4; ++i) {
                __builtin_amdgcn_global_load_lds(
                    (const __attribute__((address_space(1))) u32*)(gsrc + i * 1024),
                    (__attribute__((address_space(3))) u32*)(ldst + i * 1024), 16, 0, 0);
            }
        }
        // prefetch x for chunk+1: its fb = ((chunk+1)-1)*16 = chunk*16
        f32x4 pfn = pf;
        if (chunk <= 7) pfn = *(const f32x4*)(ghr + chunk * 16 + gq * 4);

        if (chunk == 0) {
            // silu slots: thread covers features gq*32 .. gq*32+31
            f32x4 xv[8];
#pragma unroll
            for (int v = 0; v < 8; ++v) xv[v] = *(const f32x4*)(ghr + gq * 32 + v * 4);
#pragma unroll
            for (int sl = 0; sl < 4; ++sl) {
                int s = gq * 4 + sl;
                unsigned short pk[8];
#pragma unroll
                for (int j = 0; j < 4; ++j) {
                    pk[j] = f2bf(siluf(xv[2 * sl][j]));
                    pk[4 + j] = f2bf(siluf(xv[2 * sl + 1][j]));
                }
                *(bf16x8*)((char*)A_lds + gm * 256 + (((s ^ (gm & 7)) & 15) << 4)) =
                    *(bf16x8*)pk;
            }
        } else {
            // closed-form cardinal cubic B-spline on the uniform grid (see R4 notes)
#pragma unroll
            for (int j = 0; j < 4; ++j) {
                float x = pf[j];
                float t = (x + 2.2f) * 2.5f;
                float fl = floorf(t);
                int i0 = (int)fl;
                float u = t - fl;
                float um = 1.0f - u;
                float u2 = u * u, u3 = u2 * u;
                const float c6 = 1.0f / 6.0f;
                float w0 = um * um * um * c6;
                float w1 = (3.f * u3 - 6.f * u2 + 4.f) * c6;
                float w2 = (-3.f * u3 + 3.f * u2 + 3.f * u + 1.f) * c6;
                float w3 = u3 * c6;
                u64 Wp = (u64)f2bf(w0) | ((u64)f2bf(w1) << 16) |
                         ((u64)f2bf(w2) << 32) | ((u64)f2bf(w3) << 48);
                int sh = (i0 - 3) * 16;  // slot j0 = i0-3, 16 bits per bf16 slot
                u64 lo = 0, hi = 0;
                if (sh >= 0) {
                    if (sh < 64) {
                        lo = Wp << sh;
                        hi = sh ? (Wp >> (64 - sh)) : 0;
                    } else if (sh < 128) {
                        hi = Wp << (sh - 64);
                    }
                } else {
                    int r = -sh;
                    if (r < 64) lo = Wp >> r;
                }
                int s = gq * 4 + j;
                ulonglong2 pv; pv.x = lo; pv.y = hi;
                *(ulonglong2*)((char*)A_lds + gm * 256 + (((s ^ (gm & 7)) & 15) << 4)) = pv;
            }
        }
        __syncthreads();  // drains vmcnt (global_load_lds) + lgkm (ds_write)

        // MFMA: 4 k-steps of 32, 2x4 fragments per wave
#pragma unroll
        for (int kk = 0; kk < 4; ++kk) {
            bf16x8 af[2], bfr[4];
#pragma unroll
            for (int im = 0; im < 2; ++im) {
                int mrow = wm0 + im * 16 + (lane & 15);
                int slot = (kk * 4 + (lane >> 4)) ^ (mrow & 7);
                af[im] = *(const bf16x8*)((const char*)A_lds + mrow * 256 + slot * 16);
            }
#pragma unroll
            for (int in = 0; in < 4; ++in) {
                int orow = wn0 + in * 16 + (lane & 15);
                int slot = (kk * 4 + (lane >> 4)) ^ (orow & 7);
                bfr[in] = *(const bf16x8*)((const char*)B_lds + orow * 256 + slot * 16);
            }
#pragma unroll
            for (int im = 0; im < 2; ++im)
#pragma unroll
                for (int in = 0; in < 4; ++in)
                    acc[im][in] = __builtin_amdgcn_mfma_f32_16x16x32_bf16(
                        af[im], bfr[in], acc[im][in], 0, 0, 0);
        }
        __syncthreads();
        pf = pfn;
    }

    // batched score loads (issued early; latency hides under the epilogue)
    float wa0 = wa[lane], wa1 = wa[64 + lane];
    float wa2 = wa[128 + lane], wa3 = wa[192 + lane];
    float sx0[16], sx1[16];
    const int r0 = gm0 + wid * 16;
#pragma unroll
    for (int rr = 0; rr < 16; ++rr) {
        const float* hr = h + (size_t)min(r0 + rr, N - 1) * 128;
        sx0[rr] = hr[lane];
        sx1[rr] = hr[64 + lane];
    }

    // epilogue: acc -> bf16 via LDS (reuse A_lds), then vectorized global store.
    // C swizzle: xor bits 5-6 of the in-row byte with (row>>2)&3 — the 4 row-quad
    // groups of a wave land in 4 distinct 32B windows -> all 32 banks used
    // (the old (row&7)<<4 xor had rows ≡ 0,4 mod 8 only -> 16 banks, 4-way conflict).
#pragma unroll
    for (int im = 0; im < 2; ++im) {
        int rbase = wm0 + im * 16 + ((lane >> 4) << 2);
#pragma unroll
        for (int in = 0; in < 4; ++in) {
            int col = wn0 + in * 16 + (lane & 15);
#pragma unroll
            for (int r = 0; r < 4; ++r) {
                int row = rbase + r;
                int byte = row * 256 + ((col * 2) ^ (((row >> 2) & 3) << 5));
                *(unsigned short*)((char*)A_lds + byte) = f2bf(acc[im][in][r]);
            }
        }
    }
    __syncthreads();
    for (int i = tid; i < BM * 16; i += NTHR) {
        int row = i >> 4, s = i & 15;
        int byte = row * 256 + ((s << 4) ^ (((row >> 2) & 3) << 5));
        bf16x8 v = *(bf16x8*)((char*)A_lds + byte);
        int grow = gm0 + row;
        if (grow < N) *(bf16x8*)((char*)kanb + (size_t)grow * 256 + s * 16) = v;
    }

    // score reductions (16 independent shuffle-reduce chains)
#pragma unroll
    for (int rr = 0; rr < 16; ++rr) {
        float s1 = fmaf(sx0[rr], wa0, sx1[rr] * wa1);
        float s2 = fmaf(sx0[rr], wa2, sx1[rr] * wa3);
#pragma unroll
        for (int off = 32; off; off >>= 1) {
            s1 += __shfl_xor(s1, off, 64);
            s2 += __shfl_xor(s2, off, 64);
        }
        int grow = r0 + rr;
        if (lane == 0 && grow < N) {
            s_src[grow] = s1;
            s_dst[grow] = s2;
        }
    }
}

// ---------- coalesced scan (3 tiny kernels) ----------
__global__ void k_scan1(const int* __restrict__ counts, int* __restrict__ bsum, int N) {
    int tid = threadIdx.x;
    int idx = blockIdx.x * 256 + tid;
    int v = (idx < N) ? counts[idx] : 0;
#pragma unroll
    for (int off = 32; off; off >>= 1) v += __shfl_xor(v, off, 64);
    __shared__ int ws[4];
    if ((tid & 63) == 0) ws[tid >> 6] = v;
    __syncthreads();
    if (tid == 0) bsum[blockIdx.x] = ws[0] + ws[1] + ws[2] + ws[3];
}

__global__ __launch_bounds__(1024) void k_scan2(const int* __restrict__ bsum,
                                                int* __restrict__ ebase,
                                                int* __restrict__ offsN, int nb) {
    __shared__ int ws[16];
    __shared__ int tot;
    int tid = threadIdx.x;
    int lane = tid & 63, w = tid >> 6;
    int v = (tid < nb) ? bsum[tid] : 0;
    int inc = v;
#pragma unroll
    for (int off = 1; off < 64; off <<= 1) {
        int t = __shfl_up(inc, off, 64);
        if (lane >= off) inc += t;
    }
    if (lane == 63) ws[w] = inc;
    __syncthreads();
    if (w == 0 && lane < 16) {
        int x = ws[lane];
#pragma unroll
        for (int off = 1; off < 16; off <<= 1) {
            int t = __shfl_up(x, off, 64);
            if (lane >= off) x += t;
        }
        ws[lane] = x;
        if (lane == 15) tot = x;
    }
    __syncthreads();
    int wb = w ? ws[w - 1] : 0;
    if (tid < nb) ebase[tid] = wb + inc - v;  // exclusive
    if (tid == 0) offsN[0] = tot;
}

__global__ void k_scan3(const int* __restrict__ counts, const int* __restrict__ ebase,
                        int* __restrict__ offsets, int N) {
    int tid = threadIdx.x;
    int idx = blockIdx.x * 256 + tid;
    int v = (idx < N) ? counts[idx] : 0;
    int lane = tid & 63, w = tid >> 6;
    int inc = v;
#pragma unroll
    for (int off = 1; off < 64; off <<= 1) {
        int t = __shfl_up(inc, off, 64);
        if (lane >= off) inc += t;
    }
    __shared__ int ws[4];
    if (lane == 63) ws[w] = inc;
    __syncthreads();
    int wb = 0;
    for (int i = 0; i < w; ++i) wb += ws[i];
    if (idx < N) offsets[idx] = ebase[blockIdx.x] + wb + inc - v;
}

// ---------- per-row softmax + bf16 gather-sum, in-register canonical sort ----------
__global__ __launch_bounds__(256) void k_aggr(const int* __restrict__ offsets,
                                              int* __restrict__ cols,
                                              const float* __restrict__ s_src,
                                              const float* __restrict__ s_dst,
                                              const unsigned short* __restrict__ kanb,
                                              float* __restrict__ out, int N) {
    int wid = (blockIdx.x * 256 + threadIdx.x) >> 6;
    int lane = threadIdx.x & 63;
    if (wid >= N) return;
    int start = offsets[wid], end = offsets[wid + 1];
    int deg = end - start;
    float acc0 = 0.f, acc1 = 0.f;
    if (deg > 0) {
        float ssrc = s_src[wid];
        if (deg <= 64) {
            int key = 0x7fffffff;
            if (lane < deg) key = cols[start + lane];
            // 64-wide bitonic sort, ascending (canonical order -> determinism)
#pragma unroll
            for (int k = 2; k <= 64; k <<= 1) {
#pragma unroll
                for (int j = k >> 1; j > 0; j >>= 1) {
                    int other = __shfl_xor(key, j, 64);
                    bool asc = ((lane & k) == 0);
                    bool lowr = ((lane & j) == 0);
                    int mn = min(key, other), mx = max(key, other);
                    key = (asc == lowr) ? mn : mx;
                }
            }
            float e = -3.402823466e38f;
            if (lane < deg) {
                e = ssrc + s_dst[key];
                e = (e >= 0.f) ? e : 0.2f * e;
            }
            float m = e;
#pragma unroll
            for (int off = 32; off; off >>= 1) m = fmaxf(m, __shfl_xor(m, off, 64));
            float ex = (lane < deg) ? __expf(e - m) : 0.f;
            float s = ex;
#pragma unroll
            for (int off = 32; off; off >>= 1) s += __shfl_xor(s, off, 64);
            float att = ex / s;
            // software-pipelined gather: 8 row-loads in flight, prefetch overlaps FMA
            u32 pbuf[8];
            float wbuf[8];
#pragma unroll
            for (int t = 0; t < 8; ++t) {
                int qc = (t < deg) ? t : 0;
                int c = __shfl(key, qc, 64);
                wbuf[t] = (t < deg) ? __shfl(att, qc, 64) : 0.f;
                pbuf[t] = ((const u32*)(kanb + (size_t)c * 128))[lane];
            }
            for (int q0 = 0; q0 < deg; q0 += 8) {
                u32 pc[8];
                float wc[8];
#pragma unroll
                for (int t = 0; t < 8; ++t) { pc[t] = pbuf[t]; wc[t] = wbuf[t]; }
                if (q0 + 8 < deg) {  // wave-uniform guard
#pragma unroll
                    for (int t = 0; t < 8; ++t) {
                        int q = q0 + 8 + t;
                        int qc = (q < deg) ? q : 0;
                        int c = __shfl(key, qc, 64);
                        wbuf[t] = (q < deg) ? __shfl(att, qc, 64) : 0.f;
                        pbuf[t] = ((const u32*)(kanb + (size_t)c * 128))[lane];
                    }
                }
#pragma unroll
                for (int t = 0; t < 8; ++t) {
                    float lo = __builtin_bit_cast(float, pc[t] << 16);
                    float hi = __builtin_bit_cast(float, pc[t] & 0xffff0000u);
                    acc0 = fmaf(wc[t], lo, acc0);
                    acc1 = fmaf(wc[t], hi, acc1);
                }
            }
        } else {
            // rare fallback: lane0 insertion-sorts the segment in place, then memory path
            if (lane == 0) {
                for (int i = start + 1; i < end; ++i) {
                    int v = cols[i];
                    int j = i - 1;
                    while (j >= start && cols[j] > v) { cols[j + 1] = cols[j]; --j; }
                    cols[j + 1] = v;
                }
            }
            __threadfence();
            float m = -3.402823466e38f;
            for (int j = start + lane; j < end; j += 64) {
                float e = ssrc + s_dst[cols[j]];
                e = (e >= 0.f) ? e : 0.2f * e;
                m = fmaxf(m, e);
            }
#pragma unroll
            for (int off = 32; off; off >>= 1) m = fmaxf(m, __shfl_xor(m, off, 64));
            float s = 0.f;
            for (int j = start + lane; j < end; j += 64) {
                float e = ssrc + s_dst[cols[j]];
                e = (e >= 0.f) ? e : 0.2f * e;
                s += __expf(e - m);
            }
#pragma unroll
            for (int off = 32; off; off >>= 1) s += __shfl_xor(s, off, 64);
            float inv = 1.0f / s;
            for (int t = start; t < end; t += 64) {
                int j = t + lane;
                float att = 0.f;
                int myc = 0;
                if (j < end) {
                    myc = cols[j];
                    float e = ssrc + s_dst[myc];
                    e = (e >= 0.f) ? e : 0.2f * e;
                    att = __expf(e - m) * inv;
                }
                int cnt = min(64, end - t);
                for (int q = 0; q < cnt; ++q) {
                    float w = __shfl(att, q, 64);
                    int c = __shfl(myc, q, 64);
                    u32 p = ((const u32*)(kanb + (size_t)c * 128))[lane];
                    float lo = __builtin_bit_cast(float, p << 16);
                    float hi = __builtin_bit_cast(float, p & 0xffff0000u);
                    acc0 = fmaf(w, lo, acc0);
                    acc1 = fmaf(w, hi, acc1);
                }
            }
        }
    }
    float2 o2 = make_float2(acc0, acc1);
    *(float2*)(out + (size_t)wid * 128 + lane * 2) = o2;
}

extern "C" void kernel_launch(void* const* d_in, const int* in_sizes, int n_in,
                              void* d_out, int out_size, void* d_ws, size_t ws_size,
                              hipStream_t stream) {
    const float* h  = (const float*)d_in[0];
    const int*   ei = (const int*)d_in[1];
    const float* W  = (const float*)d_in[2];
    const float* a  = (const float*)d_in[3];
    const float* bw = (const float*)d_in[4];
    const float* sw = (const float*)d_in[5];
    float* out = (float*)d_out;
    const int N = in_sizes[0] / 128;
    const int E = in_sizes[1] / 2;
    const int nb = (N + 255) / 256;
    const int nbn = (N + BM - 1) / BM;              // node tiles
    const int nbs = (E + NTHR - 1) / NTHR;          // scatter tail blocks
    const int nbh = (E + 255) / 256;                // hist tail blocks

    char* ws = (char*)d_ws;
    auto alloc = [&](size_t bytes) {
        char* p = ws;
        ws += (bytes + 255) & ~(size_t)255;
        return p;
    };
    unsigned short* Bsw = (unsigned short*)alloc((size_t)NCHUNK * 128 * 128 * 2);
    float* wa    = (float*)alloc(256 * 4);
    float* ssrc  = (float*)alloc((size_t)N * 4);
    float* sdst  = (float*)alloc((size_t)N * 4);
    unsigned short* kanb = (unsigned short*)alloc((size_t)N * 128 * 2);
    int* counts  = (int*)alloc((size_t)N * 4);      // counts+cursor contiguous: one memset
    int* cursor  = (int*)alloc((size_t)N * 4);
    int* offsets = (int*)alloc(((size_t)N + 1) * 4);
    int* colss   = (int*)alloc((size_t)E * 4);
    int* bsum    = (int*)alloc((size_t)nb * 4);
    int* ebase   = (int*)alloc((size_t)nb * 4);

    size_t npad = ((size_t)N * 4 + 255) & ~(size_t)255;
    hipMemsetAsync(counts, 0, npad + (size_t)N * 4, stream);  // zeroes counts AND cursor

    k_prep<<<PREPB + 1 + nbh, 256, 0, stream>>>(bw, sw, W, a, Bsw, wa, ei, counts, E);
    k_scan1<<<nb, 256, 0, stream>>>(counts, bsum, N);
    k_scan2<<<1, 1024, 0, stream>>>(bsum, ebase, offsets + N, nb);
    k_scan3<<<nb, 256, 0, stream>>>(counts, ebase, offsets, N);
    k_nodes<<<nbn + nbs, NTHR, 0, stream>>>(h, Bsw, wa, kanb, ssrc, sdst, N, nbn,
                                            ei, ei + E, offsets, cursor, colss, E);
    k_aggr<<<(N + 3) / 4, 256, 0, stream>>>(offsets, colss, ssrc, sdst, kanb, out, N);
}